// Round 8
// baseline (785.004 us; speedup 1.0000x reference)
//
#include <hip/hip_runtime.h>

// ---------------------------------------------------------------------------
// Nystrom attention: split-bf16 (hi/lo, 3xMFMA) everywhere.
// R13: attention kernels de-LDS'd — Q operand fragments are loop-invariant
// 16B global slices, hoisted to registers (no Qh/Ql staging). LDS for
// attn3v/attn1t2_conv drops 55.8 -> 37 KB => 3-4 blocks/CU (was 2),
// doubling latency hiding across their 16-barrier serial chains.
// Everything else as R12 (2-phase dbuf plane GEMMs, global_load_lds).
// B=4, N=4096, DIM=512, H=8, DH=64, M=256, l=16, 6 pinv iters, conv K=33.
// ---------------------------------------------------------------------------

typedef __attribute__((ext_vector_type(8))) short bf16x8;
typedef __attribute__((ext_vector_type(4))) float f32x4;

// workspace layout (float units)
constexpr size_t O_XP  = 0;          // Xh/Xl planes; later pool B (ZN/ZT/Y2T, A2T)
constexpr size_t O_QP  = 8388608;    // q planes (hi/lo)
constexpr size_t O_KP  = 16777216;   // k planes; later pool A (A2P/XZN/XZT/Y1T); later OH planes
constexpr size_t O_VT  = 25165824;   // vT planes
constexpr size_t O_QL  = 33554432;   // qland fp32; later t2T planes
constexpr size_t O_KL  = 34078720;   // kland fp32
constexpr size_t O_QLP = 34603008;   // qland planes
constexpr size_t O_KLP = 35127296;   // kland planes
constexpr size_t O_A2  = 35651584;   // attn2 fp32 (pre-softmax scores)
constexpr size_t O_T1  = 37748736;
constexpr size_t O_RS3 = 38273024;
constexpr size_t O_SCAL= 38281216;
constexpr size_t O_CS  = 38281232;   // colsum [32][256]
constexpr size_t O_WQT = 38805520;
constexpr size_t O_WOT = 39591952;
constexpr size_t O_END = 39854096;   // ~159.4 MB

// ---------------------------------------------------------------------------
__device__ __forceinline__ void split2(float x, unsigned short& h,
                                       unsigned short& l) {
    unsigned u  = __float_as_uint(x);
    unsigned hb = (u + 0x7FFFu + ((u >> 16) & 1u)) & 0xFFFF0000u;  // RNE hi
    h = (unsigned short)(hb >> 16);
    float d = x - __uint_as_float(hb);
    l = (unsigned short)(__float_as_uint(d) >> 16);
}

__device__ __forceinline__ float b2f(unsigned short s) {
    return __uint_as_float((unsigned)s << 16);
}

__device__ __forceinline__ f32x4 mfma3(bf16x8 ah, bf16x8 al, bf16x8 bh,
                                       bf16x8 bl, f32x4 c) {
    c = __builtin_amdgcn_mfma_f32_16x16x32_bf16(ah, bh, c, 0, 0, 0);
    c = __builtin_amdgcn_mfma_f32_16x16x32_bf16(ah, bl, c, 0, 0, 0);
    c = __builtin_amdgcn_mfma_f32_16x16x32_bf16(al, bh, c, 0, 0, 0);
    return c;
}

// async global->LDS, 16 B per lane (gfx950). LDS dest = uniform base + lane*16.
__device__ __forceinline__ void g2l16(const unsigned short* g,
                                      unsigned short* l) {
    __builtin_amdgcn_global_load_lds(
        (const __attribute__((address_space(1))) void*)g,
        (__attribute__((address_space(3))) void*)l, 16, 0, 0);
}

// split a float4 into hi/lo planes, write packed uint2 at H[off], L[off]
__device__ __forceinline__ void stage_split4(float4 av, unsigned short* H,
                                             unsigned short* L, int off) {
    unsigned short h0, h1, h2, h3, l0, l1, l2, l3;
    split2(av.x, h0, l0); split2(av.y, h1, l1);
    split2(av.z, h2, l2); split2(av.w, h3, l3);
    uint2 ph, pl;
    ph.x = (unsigned)h0 | ((unsigned)h1 << 16);
    ph.y = (unsigned)h2 | ((unsigned)h3 << 16);
    pl.x = (unsigned)l0 | ((unsigned)l1 << 16);
    pl.y = (unsigned)l2 | ((unsigned)l3 << 16);
    *(uint2*)&H[off] = ph;
    *(uint2*)&L[off] = pl;
}

// ---------------------------------------------------------------------------
// X -> split planes (one-time)
// ---------------------------------------------------------------------------
__global__ void xsplit(const float* __restrict__ X,
                       unsigned short* __restrict__ Xh,
                       unsigned short* __restrict__ Xl) {
    int idx = blockIdx.x * 256 + threadIdx.x;
    float4 v = *(const float4*)(X + (size_t)idx * 4);
    stage_split4(v, Xh, Xl, idx * 4);
}

// ---------------------------------------------------------------------------
// both weight transposes in one dispatch. grid 4096.
// ---------------------------------------------------------------------------
__global__ void wtrans2(const float* __restrict__ Wq,
                        const float* __restrict__ Wo,
                        unsigned short* __restrict__ QTh,
                        unsigned short* __restrict__ QTl,
                        unsigned short* __restrict__ OTh,
                        unsigned short* __restrict__ OTl) {
    int idx = blockIdx.x * 256 + threadIdx.x;
    unsigned short h, l;
    if (idx < 786432) {
        int n = idx >> 9, kk = idx & 511;
        split2(Wq[(size_t)kk * 1536 + n], h, l);
        QTh[idx] = h;
        QTl[idx] = l;
    } else {
        int j = idx - 786432;
        int n = j >> 9, kk = j & 511;
        split2(Wo[(size_t)kk * 512 + n], h, l);
        OTh[j] = h;
        OTl[j] = l;
    }
}

// ---------------------------------------------------------------------------
// All-plane pinv GEMM stage: C = alpha*(A@B) + beta*A_elem.
// SC=0: as-is. SC=1: alpha := 1/denom (EPI=0). SC=2: whole result *= 1/denom.
// A = normal planes AN[m][k]; B = transposed planes BT[n][k].
// 2-phase double-buffered global_load_lds staging. grid (4,4,32), 256 thr.
// ---------------------------------------------------------------------------
template <int EPI, int SC, bool WN, bool WTT>
__global__ __launch_bounds__(256) void mfma_gemm_p(
    const unsigned short* __restrict__ ANh, const unsigned short* __restrict__ ANl,
    const unsigned short* __restrict__ BTh, const unsigned short* __restrict__ BTl,
    unsigned short* __restrict__ CNh, unsigned short* __restrict__ CNl,
    unsigned short* __restrict__ CTh, unsigned short* __restrict__ CTl,
    float alpha, float beta, const float* __restrict__ scal) {
    __shared__ __align__(16) unsigned short Ah[2][2048], Al[2][2048];
    __shared__ __align__(16) unsigned short Bh[2][2048], Bl[2][2048];
    const int t = threadIdx.x;
    const int wave = t >> 6, lane = t & 63, lm = lane & 15, lq = lane >> 4;
    const int z = blockIdx.z;
    const int m0 = blockIdx.y * 64, n0 = blockIdx.x * 64;
    const size_t zo = (size_t)z * 65536;

    // staging role: wave 0->Ah, 1->Al, 2->Bh, 3->Bl
    const unsigned short* gsrc;
    unsigned short (*ldst)[2048];
    if (wave == 0)      { gsrc = ANh + zo + (size_t)m0 * 256; ldst = Ah; }
    else if (wave == 1) { gsrc = ANl + zo + (size_t)m0 * 256; ldst = Al; }
    else if (wave == 2) { gsrc = BTh + zo + (size_t)n0 * 256; ldst = Bh; }
    else                { gsrc = BTl + zo + (size_t)n0 * 256; ldst = Bl; }
    const int srow = lane >> 2, sko = (lane & 3) * 8;

    auto stage = [&](int b, int kt) {
#pragma unroll
        for (int c = 0; c < 4; ++c)
            g2l16(gsrc + (size_t)(c * 16 + srow) * 256 + kt + sko,
                  &ldst[b][c * 512]);
    };

    f32x4 acc[4];
#pragma unroll
    for (int j = 0; j < 4; ++j) acc[j] = (f32x4){0.f, 0.f, 0.f, 0.f};

    stage(0, 0);
    __syncthreads();
    int cur = 0;
    for (int kt = 0; kt < 256; kt += 32) {
        if (kt + 32 < 256) stage(cur ^ 1, kt + 32);
        bf16x8 ah = *(const bf16x8*)&Ah[cur][(wave * 16 + lm) * 32 + lq * 8];
        bf16x8 al = *(const bf16x8*)&Al[cur][(wave * 16 + lm) * 32 + lq * 8];
#pragma unroll
        for (int j = 0; j < 4; ++j) {
            bf16x8 bh = *(const bf16x8*)&Bh[cur][(j * 16 + lm) * 32 + lq * 8];
            bf16x8 bl = *(const bf16x8*)&Bl[cur][(j * 16 + lm) * 32 + lq * 8];
            acc[j] = mfma3(ah, al, bh, bl, acc[j]);
        }
        __syncthreads();
        cur ^= 1;
    }

    const float scv = (SC != 0) ? 1.0f / (scal[0] + 1e-8f) : 1.0f;
    const float a = (SC == 1) ? scv : alpha;
    const int r0 = m0 + wave * 16 + lq * 4;
#pragma unroll
    for (int j = 0; j < 4; ++j) {
        int c = n0 + j * 16 + lm;
        float vals[4];
#pragma unroll
        for (int e = 0; e < 4; ++e) {
            float v = a * acc[j][e];
            if (EPI == 1) {
                size_t ao = zo + (size_t)(r0 + e) * 256 + c;
                v += beta * (b2f(ANh[ao]) + b2f(ANl[ao]));
            }
            if (SC == 2) v *= scv;
            vals[e] = v;
        }
        unsigned short hh[4], ll[4];
#pragma unroll
        for (int e = 0; e < 4; ++e) split2(vals[e], hh[e], ll[e]);
        if (WN) {
#pragma unroll
            for (int e = 0; e < 4; ++e) {
                size_t o = zo + (size_t)(r0 + e) * 256 + c;
                CNh[o] = hh[e];
                CNl[o] = ll[e];
            }
        }
        if (WTT) {
            uint2 ph, pl;
            ph.x = (unsigned)hh[0] | ((unsigned)hh[1] << 16);
            ph.y = (unsigned)hh[2] | ((unsigned)hh[3] << 16);
            pl.x = (unsigned)ll[0] | ((unsigned)ll[1] << 16);
            pl.y = (unsigned)ll[2] | ((unsigned)ll[3] << 16);
            *(uint2*)&CTh[zo + (size_t)c * 256 + r0] = ph;
            *(uint2*)&CTl[zo + (size_t)c * 256 + r0] = pl;
        }
    }
}

// fp32 64x64 micro-kernel
__device__ __forceinline__ void mt16(const float* As, const float* Bs,
                                     int ty4, int tx4, float (&acc)[4][4]) {
#pragma unroll
    for (int kk = 0; kk < 16; ++kk) {
        float4 a4 = *(const float4*)(As + kk * 68 + ty4);
        float4 b4 = *(const float4*)(Bs + kk * 68 + tx4);
        float aa[4] = {a4.x, a4.y, a4.z, a4.w};
        float bb[4] = {b4.x, b4.y, b4.z, b4.w};
#pragma unroll
        for (int u = 0; u < 4; ++u)
#pragma unroll
            for (int w = 0; w < 4; ++w)
                acc[u][w] += aa[u] * bb[w];
    }
}

// ---------------------------------------------------------------------------
// t2 = z6 @ (t1/rs3): A from ZN planes (h+l recombine). grid (1,4,32).
// Emits t2^T planes only (stride 16384/z).
// ---------------------------------------------------------------------------
__global__ __launch_bounds__(256) void t2_gemm(
    const unsigned short* __restrict__ ANh, const unsigned short* __restrict__ ANl,
    const float* __restrict__ t1, const float* __restrict__ rs3,
    unsigned short* __restrict__ t2Th, unsigned short* __restrict__ t2Tl) {
    __shared__ float As[16 * 68];
    __shared__ float Bs[16 * 68];
    const int t  = threadIdx.x;
    const int z  = blockIdx.z;
    const int m0 = blockIdx.y * 64;
    const size_t zo = (size_t)z * 65536;
    const float* Bb = t1 + (size_t)z * 16384;
    const int tx4 = (t & 15) * 4;
    const int ty4 = (t >> 4) * 4;
    const int ar  = t >> 2, ak = (t & 3) * 4;
    const int bkr = t >> 4, bc4 = (t & 15) * 4;
    float acc[4][4] = {};
    for (int kt = 0; kt < 256; kt += 16) {
        uint2 h2 = *(const uint2*)(ANh + zo + (size_t)(m0 + ar) * 256 + kt + ak);
        uint2 l2 = *(const uint2*)(ANl + zo + (size_t)(m0 + ar) * 256 + kt + ak);
        const unsigned short* hp = (const unsigned short*)&h2;
        const unsigned short* lp = (const unsigned short*)&l2;
        float4 av = make_float4(b2f(hp[0]) + b2f(lp[0]), b2f(hp[1]) + b2f(lp[1]),
                                b2f(hp[2]) + b2f(lp[2]), b2f(hp[3]) + b2f(lp[3]));
        float4 bv = *(const float4*)(Bb + (size_t)(kt + bkr) * 64 + bc4);
        float rr = 1.0f / rs3[z * 256 + kt + bkr];
        bv.x *= rr; bv.y *= rr; bv.z *= rr; bv.w *= rr;
        As[(ak + 0) * 68 + ar] = av.x;
        As[(ak + 1) * 68 + ar] = av.y;
        As[(ak + 2) * 68 + ar] = av.z;
        As[(ak + 3) * 68 + ar] = av.w;
        *(float4*)(Bs + bkr * 68 + bc4) = bv;
        __syncthreads();
        mt16(As, Bs, ty4, tx4, acc);
        __syncthreads();
    }
#pragma unroll
    for (int w = 0; w < 4; ++w) {
        unsigned short hh[4], ll[4];
#pragma unroll
        for (int u = 0; u < 4; ++u) split2(acc[u][w], hh[u], ll[u]);
        uint2 ph, pl;
        ph.x = (unsigned)hh[0] | ((unsigned)hh[1] << 16);
        ph.y = (unsigned)hh[2] | ((unsigned)hh[3] << 16);
        pl.x = (unsigned)ll[0] | ((unsigned)ll[1] << 16);
        pl.y = (unsigned)ll[2] | ((unsigned)ll[3] << 16);
        size_t off = (size_t)z * 16384 + (size_t)(tx4 + w) * 256 + m0 + ty4;
        *(uint2*)&t2Th[off] = ph;
        *(uint2*)&t2Tl[off] = pl;
    }
}

// ---------------------------------------------------------------------------
// qkv MFMA GEMM: X planes [16384,512] @ w_qkv planes; emits q/k planes
// ([bh][n][d], q scaled 0.125) and vT planes [bh][dh][4096]. grid (12,128).
// 2-phase double-buffered global_load_lds staging.
// ---------------------------------------------------------------------------
__global__ __launch_bounds__(256) void mfma_qkv(
    const unsigned short* __restrict__ Xh_, const unsigned short* __restrict__ Xl_,
    const unsigned short* __restrict__ WTh, const unsigned short* __restrict__ WTl,
    unsigned short* __restrict__ qh, unsigned short* __restrict__ ql,
    unsigned short* __restrict__ kh, unsigned short* __restrict__ kl,
    unsigned short* __restrict__ vTh, unsigned short* __restrict__ vTl) {
    __shared__ __align__(16) unsigned short Ah[2][4096], Al[2][4096];
    __shared__ __align__(16) unsigned short Bh[2][4096], Bl[2][4096];
    const int t = threadIdx.x;
    const int wave = t >> 6, lane = t & 63, lm = lane & 15, lq = lane >> 4;
    // XCD-aware bijective swizzle: nwg=1536, 1536/8=192 per XCD
    int orig = blockIdx.y * 12 + blockIdx.x;
    int wg = (orig & 7) * 192 + (orig >> 3);
    const int m0 = (wg / 12) * 128, n0 = (wg % 12) * 128;
    const int mb = (wave >> 1) * 64, nb = (wave & 1) * 64;

    // staging role
    const unsigned short* gsrc;
    unsigned short (*ldst)[4096];
    if (wave == 0)      { gsrc = Xh_ + (size_t)m0 * 512; ldst = Ah; }
    else if (wave == 1) { gsrc = Xl_ + (size_t)m0 * 512; ldst = Al; }
    else if (wave == 2) { gsrc = WTh + (size_t)n0 * 512; ldst = Bh; }
    else                { gsrc = WTl + (size_t)n0 * 512; ldst = Bl; }
    const int srow = lane >> 2, sko = (lane & 3) * 8;

    auto stage = [&](int b, int kt) {
#pragma unroll
        for (int c = 0; c < 8; ++c)
            g2l16(gsrc + (size_t)(c * 16 + srow) * 512 + kt + sko,
                  &ldst[b][c * 512]);
    };

    f32x4 acc[4][4];
#pragma unroll
    for (int i = 0; i < 4; ++i)
#pragma unroll
        for (int j = 0; j < 4; ++j) acc[i][j] = (f32x4){0.f, 0.f, 0.f, 0.f};

    stage(0, 0);
    __syncthreads();
    int cur = 0;
    for (int kt = 0; kt < 512; kt += 32) {
        if (kt + 32 < 512) stage(cur ^ 1, kt + 32);
        bf16x8 ah[4], al[4], bh[4], bl[4];
#pragma unroll
        for (int i = 0; i < 4; ++i) {
            ah[i] = *(const bf16x8*)&Ah[cur][(mb + i * 16 + lm) * 32 + lq * 8];
            al[i] = *(const bf16x8*)&Al[cur][(mb + i * 16 + lm) * 32 + lq * 8];
        }
#pragma unroll
        for (int j = 0; j < 4; ++j) {
            bh[j] = *(const bf16x8*)&Bh[cur][(nb + j * 16 + lm) * 32 + lq * 8];
            bl[j] = *(const bf16x8*)&Bl[cur][(nb + j * 16 + lm) * 32 + lq * 8];
        }
#pragma unroll
        for (int i = 0; i < 4; ++i)
#pragma unroll
            for (int j = 0; j < 4; ++j)
                acc[i][j] = mfma3(ah[i], al[i], bh[j], bl[j], acc[i][j]);
        __syncthreads();
        cur ^= 1;
    }
#pragma unroll
    for (int i = 0; i < 4; ++i)
#pragma unroll
        for (int j = 0; j < 4; ++j) {
            int r0 = m0 + mb + i * 16 + lq * 4;
            int c  = n0 + nb + j * 16 + lm;
            int which = c >> 9, h = (c >> 6) & 7, d = c & 63;
            int b = r0 >> 12, nbase = r0 & 4095;
            if (which == 2) {
                unsigned short hh[4], ll[4];
#pragma unroll
                for (int e = 0; e < 4; ++e) split2(acc[i][j][e], hh[e], ll[e]);
                uint2 ph, pl;
                ph.x = (unsigned)hh[0] | ((unsigned)hh[1] << 16);
                ph.y = (unsigned)hh[2] | ((unsigned)hh[3] << 16);
                pl.x = (unsigned)ll[0] | ((unsigned)ll[1] << 16);
                pl.y = (unsigned)ll[2] | ((unsigned)ll[3] << 16);
                size_t off = ((size_t)(b * 8 + h) * 64 + d) * 4096 + nbase;
                *(uint2*)&vTh[off] = ph;
                *(uint2*)&vTl[off] = pl;
            } else {
                unsigned short* Ph = which ? kh : qh;
                unsigned short* Pl = which ? kl : ql;
                float sc = which ? 1.0f : 0.125f;
#pragma unroll
                for (int e = 0; e < 4; ++e) {
                    unsigned short hh, ll;
                    split2(acc[i][j][e] * sc, hh, ll);
                    size_t off = (size_t)(b * 8 + h) * 262144 +
                                 (size_t)(nbase + e) * 64 + d;
                    Ph[off] = hh;
                    Pl[off] = ll;
                }
            }
        }
}

// ---------------------------------------------------------------------------
// final MFMA GEMM: out[16384,512] = OH planes (gathered) @ w_out planes.
// grid (4,128). 2-phase double-buffered global_load_lds (A via gather).
// ---------------------------------------------------------------------------
__global__ __launch_bounds__(256) void mfma_final(
    const unsigned short* __restrict__ OHh, const unsigned short* __restrict__ OHl,
    const unsigned short* __restrict__ WTh, const unsigned short* __restrict__ WTl,
    float* __restrict__ out) {
    __shared__ __align__(16) unsigned short Ah[2][4096], Al[2][4096];
    __shared__ __align__(16) unsigned short Bh[2][4096], Bl[2][4096];
    const int t = threadIdx.x;
    const int wave = t >> 6, lane = t & 63, lm = lane & 15, lq = lane >> 4;
    // XCD-aware bijective swizzle: nwg=512, 512/8=64 per XCD
    int orig = blockIdx.y * 4 + blockIdx.x;
    int wg = (orig & 7) * 64 + (orig >> 3);
    const int m0 = (wg >> 2) * 128, n0 = (wg & 3) * 128;
    const int mb = (wave >> 1) * 64, nb = (wave & 1) * 64;

    const bool isA = wave < 2;
    const unsigned short* gA = (wave == 0) ? OHh : OHl;
    const unsigned short* gB = (wave == 2) ? WTh : WTl;
    unsigned short (*ldst)[4096] = (wave == 0) ? Ah : (wave == 1) ? Al
                                 : (wave == 2) ? Bh : Bl;
    const int srow = lane >> 2, sko = (lane & 3) * 8;
    // A-gather constants per chunk
    int gb[8], gn[8];
#pragma unroll
    for (int c = 0; c < 8; ++c) {
        int gr = m0 + c * 16 + srow;
        gb[c] = gr >> 12;
        gn[c] = gr & 4095;
    }

    auto stage = [&](int b, int kt) {
        if (isA) {
            int kk = kt + sko;
            size_t koff = (size_t)(kk >> 6) * 262144 + (kk & 63);
#pragma unroll
            for (int c = 0; c < 8; ++c)
                g2l16(gA + (size_t)gb[c] * 2097152 + koff +
                          (size_t)gn[c] * 64,
                      &ldst[b][c * 512]);
        } else {
#pragma unroll
            for (int c = 0; c < 8; ++c)
                g2l16(gB + (size_t)(n0 + c * 16 + srow) * 512 + kt + sko,
                      &ldst[b][c * 512]);
        }
    };

    f32x4 acc[4][4];
#pragma unroll
    for (int i = 0; i < 4; ++i)
#pragma unroll
        for (int j = 0; j < 4; ++j) acc[i][j] = (f32x4){0.f, 0.f, 0.f, 0.f};

    stage(0, 0);
    __syncthreads();
    int cur = 0;
    for (int kt = 0; kt < 512; kt += 32) {
        if (kt + 32 < 512) stage(cur ^ 1, kt + 32);
        bf16x8 ah[4], al[4], bh[4], bl[4];
#pragma unroll
        for (int i = 0; i < 4; ++i) {
            ah[i] = *(const bf16x8*)&Ah[cur][(mb + i * 16 + lm) * 32 + lq * 8];
            al[i] = *(const bf16x8*)&Al[cur][(mb + i * 16 + lm) * 32 + lq * 8];
        }
#pragma unroll
        for (int j = 0; j < 4; ++j) {
            bh[j] = *(const bf16x8*)&Bh[cur][(nb + j * 16 + lm) * 32 + lq * 8];
            bl[j] = *(const bf16x8*)&Bl[cur][(nb + j * 16 + lm) * 32 + lq * 8];
        }
#pragma unroll
        for (int i = 0; i < 4; ++i)
#pragma unroll
            for (int j = 0; j < 4; ++j)
                acc[i][j] = mfma3(ah[i], al[i], bh[j], bl[j], acc[i][j]);
        __syncthreads();
        cur ^= 1;
    }
#pragma unroll
    for (int i = 0; i < 4; ++i)
#pragma unroll
        for (int j = 0; j < 4; ++j) {
            int r0 = m0 + mb + i * 16 + lq * 4;
            int c  = n0 + nb + j * 16 + lm;
#pragma unroll
            for (int e = 0; e < 4; ++e)
                out[(size_t)(r0 + e) * 512 + c] = acc[i][j][e];
        }
}

// ---------------------------------------------------------------------------
// F3 MFMA: t1 += exp(qland@k^T)@v, rs3 += rowsums. grid (8, 4, 32).
// Q fragments in registers (loop-invariant, direct global loads).
// LDS 37 KB -> 3-4 blocks/CU.
// ---------------------------------------------------------------------------
__global__ __launch_bounds__(256) void attn3v_mfma(
    const unsigned short* __restrict__ qlh, const unsigned short* __restrict__ qll,
    const unsigned short* __restrict__ kh_, const unsigned short* __restrict__ kl_,
    const unsigned short* __restrict__ vTh, const unsigned short* __restrict__ vTl,
    float* __restrict__ t1, float* __restrict__ rs3) {
    __shared__ unsigned short Kh[4608], Kl[4608];
    __shared__ unsigned short Eh[4608], El[4608];
    const int t = threadIdx.x;
    const int wave = t >> 6, lane = t & 63, lm = lane & 15, lq = lane >> 4;
    const int bz = blockIdx.z, m0 = blockIdx.y * 64, c0 = blockIdx.x * 8;
    const unsigned short* khb = kh_ + (size_t)bz * 262144;
    const unsigned short* klb = kl_ + (size_t)bz * 262144;
    const unsigned short* vhb = vTh + (size_t)bz * 262144;
    const unsigned short* vlb = vTl + (size_t)bz * 262144;
    // Q fragments: rows m0 + wave*16 + lm, cols lq*8(+32)
    {
    }
    const unsigned short* qrh = qlh + (size_t)bz * 16384 +
                                (size_t)(m0 + wave * 16 + lm) * 64;
    const unsigned short* qrl = qll + (size_t)bz * 16384 +
                                (size_t)(m0 + wave * 16 + lm) * 64;
    bf16x8 a0  = *(const bf16x8*)(qrh + lq * 8);
    bf16x8 a0l = *(const bf16x8*)(qrl + lq * 8);
    bf16x8 a1  = *(const bf16x8*)(qrh + 32 + lq * 8);
    bf16x8 a1l = *(const bf16x8*)(qrl + 32 + lq * 8);

    f32x4 acc[4];
#pragma unroll
    for (int j = 0; j < 4; ++j) acc[j] = (f32x4){0.f, 0.f, 0.f, 0.f};
    float rsum[4] = {0.f, 0.f, 0.f, 0.f};

    for (int c = c0; c < c0 + 8; ++c) {
        const int tok0 = c * 64;
#pragma unroll
        for (int r = 0; r < 2; ++r) {
            int id = t + r * 256, row = id >> 3, ko = (id & 7) * 8;
            *(uint4*)&Kh[row * 72 + ko] =
                *(const uint4*)(khb + (size_t)(tok0 + row) * 64 + ko);
            *(uint4*)&Kl[row * 72 + ko] =
                *(const uint4*)(klb + (size_t)(tok0 + row) * 64 + ko);
        }
        __syncthreads();
        f32x4 s[4];
#pragma unroll
        for (int j = 0; j < 4; ++j) s[j] = (f32x4){0.f, 0.f, 0.f, 0.f};
#pragma unroll
        for (int j = 0; j < 4; ++j) {
            bf16x8 b0  = *(const bf16x8*)&Kh[(j * 16 + lm) * 72 + lq * 8];
            bf16x8 b0l = *(const bf16x8*)&Kl[(j * 16 + lm) * 72 + lq * 8];
            bf16x8 b1  = *(const bf16x8*)&Kh[(j * 16 + lm) * 72 + 32 + lq * 8];
            bf16x8 b1l = *(const bf16x8*)&Kl[(j * 16 + lm) * 72 + 32 + lq * 8];
            s[j] = mfma3(a0, a0l, b0, b0l, s[j]);
            s[j] = mfma3(a1, a1l, b1, b1l, s[j]);
        }
        __syncthreads();
#pragma unroll
        for (int j = 0; j < 4; ++j)
#pragma unroll
            for (int e = 0; e < 4; ++e) {
                float ev = __expf(s[j][e]);
                rsum[e] += ev;
                unsigned short h, l;
                split2(ev, h, l);
                int off = (wave * 16 + lq * 4 + e) * 72 + j * 16 + lm;
                Eh[off] = h;
                El[off] = l;
            }
#pragma unroll
        for (int r = 0; r < 2; ++r) {
            int id = t + r * 256, dh = id >> 3, t8 = (id & 7) * 8;
            *(uint4*)&Kh[dh * 72 + t8] =
                *(const uint4*)(vhb + (size_t)dh * 4096 + tok0 + t8);
            *(uint4*)&Kl[dh * 72 + t8] =
                *(const uint4*)(vlb + (size_t)dh * 4096 + tok0 + t8);
        }
        __syncthreads();
        bf16x8 e0  = *(const bf16x8*)&Eh[(wave * 16 + lm) * 72 + lq * 8];
        bf16x8 e0l = *(const bf16x8*)&El[(wave * 16 + lm) * 72 + lq * 8];
        bf16x8 e1  = *(const bf16x8*)&Eh[(wave * 16 + lm) * 72 + 32 + lq * 8];
        bf16x8 e1l = *(const bf16x8*)&El[(wave * 16 + lm) * 72 + 32 + lq * 8];
#pragma unroll
        for (int j = 0; j < 4; ++j) {
            bf16x8 v0  = *(const bf16x8*)&Kh[(j * 16 + lm) * 72 + lq * 8];
            bf16x8 v0l = *(const bf16x8*)&Kl[(j * 16 + lm) * 72 + lq * 8];
            bf16x8 v1  = *(const bf16x8*)&Kh[(j * 16 + lm) * 72 + 32 + lq * 8];
            bf16x8 v1l = *(const bf16x8*)&Kl[(j * 16 + lm) * 72 + 32 + lq * 8];
            acc[j] = mfma3(e0, e0l, v0, v0l, acc[j]);
            acc[j] = mfma3(e1, e1l, v1, v1l, acc[j]);
        }
        __syncthreads();
    }
    float* t1b = t1 + (size_t)bz * 16384;
#pragma unroll
    for (int j = 0; j < 4; ++j)
#pragma unroll
        for (int e = 0; e < 4; ++e)
            atomicAdd(t1b + (size_t)(m0 + wave * 16 + lq * 4 + e) * 64 +
                          j * 16 + lm,
                      acc[j][e]);
#pragma unroll
    for (int e = 0; e < 4; ++e) {
        float vs = rsum[e];
        for (int mm = 1; mm < 16; mm <<= 1) vs += __shfl_xor(vs, mm);
        if (lm == 0)
            atomicAdd(rs3 + bz * 256 + m0 + wave * 16 + lq * 4 + e, vs);
    }
}

// ---------------------------------------------------------------------------
// F1 MFMA + fused depthwise conv: OH planes = softmax(q@kland^T)@t2 + conv(v).
// Q fragments in registers; LDS = K h/l + E h/l (37 KB); the K/E region is
// re-used as the fp32 v window Vs[96][65] for the conv tail. grid (64, 32).
// ---------------------------------------------------------------------------
__global__ __launch_bounds__(256) void attn1t2_conv(
    const unsigned short* __restrict__ qh_, const unsigned short* __restrict__ ql_,
    const unsigned short* __restrict__ klh, const unsigned short* __restrict__ kll,
    const unsigned short* __restrict__ t2Th, const unsigned short* __restrict__ t2Tl,
    const unsigned short* __restrict__ vTh, const unsigned short* __restrict__ vTl,
    const float* __restrict__ wres,
    unsigned short* __restrict__ OHh, unsigned short* __restrict__ OHl) {
    __shared__ __align__(16) unsigned short SH[18432];   // 36864 B
    unsigned short* Kh = SH;
    unsigned short* Kl = SH + 4608;
    unsigned short* Eh = SH + 9216;
    unsigned short* El = SH + 13824;
    __shared__ float Ws[33];
    const int t = threadIdx.x;
    const int wave = t >> 6, lane = t & 63, lm = lane & 15, lq = lane >> 4;
    const int bz = blockIdx.y, m0 = blockIdx.x * 64;
    if (t < 33) Ws[t] = wres[(bz & 7) * 33 + t];
    const unsigned short* khb = klh + (size_t)bz * 16384;
    const unsigned short* klb = kll + (size_t)bz * 16384;
    const unsigned short* t2h = t2Th + (size_t)bz * 16384;
    const unsigned short* t2l = t2Tl + (size_t)bz * 16384;
    // Q fragments: rows m0 + wave*16 + lm, cols lq*8(+32)
    const unsigned short* qrh = qh_ + (size_t)bz * 262144 +
                                (size_t)(m0 + wave * 16 + lm) * 64;
    const unsigned short* qrl = ql_ + (size_t)bz * 262144 +
                                (size_t)(m0 + wave * 16 + lm) * 64;
    bf16x8 a0  = *(const bf16x8*)(qrh + lq * 8);
    bf16x8 a0l = *(const bf16x8*)(qrl + lq * 8);
    bf16x8 a1  = *(const bf16x8*)(qrh + 32 + lq * 8);
    bf16x8 a1l = *(const bf16x8*)(qrl + 32 + lq * 8);

    f32x4 acc[4];
#pragma unroll
    for (int j = 0; j < 4; ++j) acc[j] = (f32x4){0.f, 0.f, 0.f, 0.f};
    float rsum[4] = {0.f, 0.f, 0.f, 0.f};

    for (int lc = 0; lc < 4; ++lc) {
        const int l0 = lc * 64;
#pragma unroll
        for (int r = 0; r < 2; ++r) {
            int id = t + r * 256, row = id >> 3, ko = (id & 7) * 8;
            *(uint4*)&Kh[row * 72 + ko] =
                *(const uint4*)(khb + (size_t)(l0 + row) * 64 + ko);
            *(uint4*)&Kl[row * 72 + ko] =
                *(const uint4*)(klb + (size_t)(l0 + row) * 64 + ko);
        }
        __syncthreads();
        f32x4 s[4];
#pragma unroll
        for (int j = 0; j < 4; ++j) s[j] = (f32x4){0.f, 0.f, 0.f, 0.f};
#pragma unroll
        for (int j = 0; j < 4; ++j) {
            bf16x8 b0  = *(const bf16x8*)&Kh[(j * 16 + lm) * 72 + lq * 8];
            bf16x8 b0l = *(const bf16x8*)&Kl[(j * 16 + lm) * 72 + lq * 8];
            bf16x8 b1  = *(const bf16x8*)&Kh[(j * 16 + lm) * 72 + 32 + lq * 8];
            bf16x8 b1l = *(const bf16x8*)&Kl[(j * 16 + lm) * 72 + 32 + lq * 8];
            s[j] = mfma3(a0, a0l, b0, b0l, s[j]);
            s[j] = mfma3(a1, a1l, b1, b1l, s[j]);
        }
        __syncthreads();
#pragma unroll
        for (int j = 0; j < 4; ++j)
#pragma unroll
            for (int e = 0; e < 4; ++e) {
                float ev = __expf(s[j][e]);
                rsum[e] += ev;
                unsigned short h, l;
                split2(ev, h, l);
                int off = (wave * 16 + lq * 4 + e) * 72 + j * 16 + lm;
                Eh[off] = h;
                El[off] = l;
            }
#pragma unroll
        for (int r = 0; r < 2; ++r) {
            int id = t + r * 256, dh = id >> 3, t8 = (id & 7) * 8;
            *(uint4*)&Kh[dh * 72 + t8] =
                *(const uint4*)(t2h + (size_t)dh * 256 + l0 + t8);
            *(uint4*)&Kl[dh * 72 + t8] =
                *(const uint4*)(t2l + (size_t)dh * 256 + l0 + t8);
        }
        __syncthreads();
        bf16x8 e0  = *(const bf16x8*)&Eh[(wave * 16 + lm) * 72 + lq * 8];
        bf16x8 e0l = *(const bf16x8*)&El[(wave * 16 + lm) * 72 + lq * 8];
        bf16x8 e1  = *(const bf16x8*)&Eh[(wave * 16 + lm) * 72 + 32 + lq * 8];
        bf16x8 e1l = *(const bf16x8*)&El[(wave * 16 + lm) * 72 + 32 + lq * 8];
#pragma unroll
        for (int j = 0; j < 4; ++j) {
            bf16x8 v0  = *(const bf16x8*)&Kh[(j * 16 + lm) * 72 + lq * 8];
            bf16x8 v0l = *(const bf16x8*)&Kl[(j * 16 + lm) * 72 + lq * 8];
            bf16x8 v1  = *(const bf16x8*)&Kh[(j * 16 + lm) * 72 + 32 + lq * 8];
            bf16x8 v1l = *(const bf16x8*)&Kl[(j * 16 + lm) * 72 + 32 + lq * 8];
            acc[j] = mfma3(e0, e0l, v0, v0l, acc[j]);
            acc[j] = mfma3(e1, e1l, v1, v1l, acc[j]);
        }
        __syncthreads();
    }
    float rinv[4];
#pragma unroll
    for (int e = 0; e < 4; ++e) {
        float vs = rsum[e];
        for (int mm = 1; mm < 16; mm <<= 1) vs += __shfl_xor(vs, mm);
        rinv[e] = 1.0f / vs;
    }

    // ---- fused conv: stage v window [m0-16, m0+80) into dead K/E LDS ----
    __syncthreads();
    float* Vs = (float*)SH;                      // 96 x 65 fp32 = 24960 B
    const unsigned short* vhb = vTh + (size_t)bz * 262144;
    const unsigned short* vlb = vTl + (size_t)bz * 262144;
#pragma unroll
    for (int r = 0; r < 3; ++r) {
        int id = t + r * 256;                    // 0..767 = 64 dh x 12 chunks
        int d = id / 12, ch = id - d * 12;
        int n = m0 - 16 + ch * 8;
        uint4 h4 = make_uint4(0u, 0u, 0u, 0u);
        uint4 l4 = make_uint4(0u, 0u, 0u, 0u);
        if ((unsigned)n < 4096u) {
            h4 = *(const uint4*)(vhb + (size_t)d * 4096 + n);
            l4 = *(const uint4*)(vlb + (size_t)d * 4096 + n);
        }
        const unsigned short* hp = (const unsigned short*)&h4;
        const unsigned short* lp = (const unsigned short*)&l4;
#pragma unroll
        for (int i = 0; i < 8; ++i)
            Vs[(ch * 8 + i) * 65 + d] = b2f(hp[i]) + b2f(lp[i]);
    }
    __syncthreads();
    unsigned short* Hh = OHh + (size_t)bz * 262144;
    unsigned short* Hl = OHl + (size_t)bz * 262144;
    const int rbase = wave * 16 + lq * 4;
#pragma unroll
    for (int j = 0; j < 4; ++j) {
        int cc = j * 16 + lm;
        float w[36];
#pragma unroll
        for (int u = 0; u < 36; ++u) w[u] = Vs[(rbase + u) * 65 + cc];
#pragma unroll
        for (int e = 0; e < 4; ++e) {
            float cv = 0.f;
#pragma unroll
            for (int tt = 0; tt < 33; ++tt) cv += w[e + tt] * Ws[tt];
            float o = acc[j][e] * rinv[e] + cv;
            unsigned short hh, ll;
            split2(o, hh, ll);
            size_t off = (size_t)(m0 + rbase + e) * 64 + cc;
            Hh[off] = hh;
            Hl[off] = ll;
        }
    }
}

// ---------------------------------------------------------------------------
// fp32 gemm for attn2 scores
// ---------------------------------------------------------------------------
__global__ __launch_bounds__(256) void gemm_a2(
    const float* __restrict__ A, const float* __restrict__ B,
    float* __restrict__ C) {
    __shared__ float As[16 * 68];
    __shared__ float Bs[16 * 68];
    const int t  = threadIdx.x;
    const int z  = blockIdx.z;
    const int m0 = blockIdx.y * 64;
    const int n0 = blockIdx.x * 64;
    const float* Ab = A + (size_t)z * 16384;
    const float* Bb = B + (size_t)z * 16384;
    float*       Cb = C + (size_t)z * 65536;
    const int tx4 = (t & 15) * 4;
    const int ty4 = (t >> 4) * 4;
    const int ar  = t >> 2, ak = (t & 3) * 4;
    float acc[4][4] = {};
    for (int kt = 0; kt < 64; kt += 16) {
        float4 av = *(const float4*)(Ab + (size_t)(m0 + ar) * 64 + kt + ak);
        float4 bv = *(const float4*)(Bb + (size_t)(n0 + ar) * 64 + kt + ak);
        As[(ak + 0) * 68 + ar] = av.x;
        As[(ak + 1) * 68 + ar] = av.y;
        As[(ak + 2) * 68 + ar] = av.z;
        As[(ak + 3) * 68 + ar] = av.w;
        Bs[(ak + 0) * 68 + ar] = bv.x;
        Bs[(ak + 1) * 68 + ar] = bv.y;
        Bs[(ak + 2) * 68 + ar] = bv.z;
        Bs[(ak + 3) * 68 + ar] = bv.w;
        __syncthreads();
        mt16(As, Bs, ty4, tx4, acc);
        __syncthreads();
    }
#pragma unroll
    for (int u = 0; u < 4; ++u) {
        int row = m0 + ty4 + u;
        *(float4*)(Cb + (size_t)row * 256 + n0 + tx4) =
            make_float4(acc[u][0], acc[u][1], acc[u][2], acc[u][3]);
    }
}

// ---------------------------------------------------------------------------
// small kernels
// ---------------------------------------------------------------------------
__global__ void zero_f(float* __restrict__ p, int n) {
    int i = blockIdx.x * 256 + threadIdx.x;
    if (i < n) p[i] = 0.f;
}

// both landmark means in one dispatch. grid 4096.
__global__ void landmark_mean2(
    const unsigned short* __restrict__ qh, const unsigned short* __restrict__ ql,
    const unsigned short* __restrict__ kh, const unsigned short* __restrict__ kl,
    float* __restrict__ qland, float* __restrict__ kland,
    unsigned short* __restrict__ qlh, unsigned short* __restrict__ qll,
    unsigned short* __restrict__ klh, unsigned short* __restrict__ kll) {
    int o = blockIdx.x * 256 + threadIdx.x;
    bool isq = o < 524288;
    int oo = isq ? o : o - 524288;
    const unsigned short* sh = isq ? qh : kh;
    const unsigned short* sl = isq ? ql : kl;
    float* dst = isq ? qland : kland;
    unsigned short* dh = isq ? qlh : klh;
    unsigned short* dl = isq ? qll : kll;
    int d = oo & 63, m = (oo >> 6) & 255, bh = oo >> 14;
    size_t base = (size_t)bh * 262144 + (size_t)m * 1024 + d;
    float acc = 0.f;
#pragma unroll
    for (int j = 0; j < 16; ++j)
        acc += b2f(sh[base + j * 64]) + b2f(sl[base + j * 64]);
    float v = acc * (1.0f / 16.0f);
    dst[oo] = v;
    unsigned short h, l;
    split2(v, h, l);
    dh[oo] = h;
    dl[oo] = l;
}

// softmax + emit a2 normal/transposed planes + colsum atomics. grid 8192.
__global__ void softmax_fused(const float* __restrict__ a,
                              unsigned short* __restrict__ A2Ph,
                              unsigned short* __restrict__ A2Pl,
                              unsigned short* __restrict__ A2Th,
                              unsigned short* __restrict__ A2Tl,
                              float* __restrict__ colsum) {
    __shared__ float red[256];
    int row = blockIdx.x, t = threadIdx.x;
    float v = a[(size_t)row * 256 + t];
    red[t] = v;
    __syncthreads();
    for (int s = 128; s > 0; s >>= 1) {
        if (t < s) red[t] = fmaxf(red[t], red[t + s]);
        __syncthreads();
    }
    float mx = red[0];
    __syncthreads();
    float e = __expf(v - mx);
    red[t] = e;
    __syncthreads();
    for (int s = 128; s > 0; s >>= 1) {
        if (t < s) red[t] += red[t + s];
        __syncthreads();
    }
    float val = e / red[0];
    int z = row >> 8, r = row & 255;
    atomicAdd(&colsum[z * 256 + t], val);
    unsigned short h, l;
    split2(val, h, l);
    size_t zo = (size_t)z * 65536;
    A2Ph[zo + (size_t)r * 256 + t] = h;
    A2Pl[zo + (size_t)r * 256 + t] = l;
    A2Th[zo + (size_t)t * 256 + r] = h;
    A2Tl[zo + (size_t)t * 256 + r] = l;
}

// global max over colsum -> scal[0]. grid 32.
__global__ void scal_max(const float* __restrict__ colsum,
                         float* __restrict__ scal) {
    __shared__ float red[256];
    int t = threadIdx.x;
    red[t] = colsum[blockIdx.x * 256 + t];
    __syncthreads();
    for (int s = 128; s > 0; s >>= 1) {
        if (t < s) red[t] = fmaxf(red[t], red[t + s]);
        __syncthreads();
    }
    if (t == 0) atomicMax((unsigned int*)&scal[0], __float_as_uint(red[0]));
}

// ---------------------------------------------------------------------------
extern "C" void kernel_launch(void* const* d_in, const int* in_sizes, int n_in,
                              void* d_out, int out_size, void* d_ws, size_t ws_size,
                              hipStream_t stream) {
    const float* x     = (const float*)d_in[0];
    const float* w_qkv = (const float*)d_in[1];
    const float* w_out = (const float*)d_in[2];
    const float* w_res = (const float*)d_in[3];
    float* out = (float*)d_out;
    float* ws  = (float*)d_ws;

    // planes (ushort units)
    unsigned short* Xh  = (unsigned short*)(ws + O_XP);
    unsigned short* Xl  = Xh + 8388608;
    unsigned short* qh  = (unsigned short*)(ws + O_QP);
    unsigned short* ql  = qh + 8388608;
    unsigned short* kh  = (unsigned short*)(ws + O_KP);
    unsigned short* kl  = kh + 8388608;
    unsigned short* vTh = (unsigned short*)(ws + O_VT);
    unsigned short* vTl = vTh + 8388608;
    unsigned short* qlh = (unsigned short*)(ws + O_QLP);
    unsigned short* qll = qlh + 524288;
    unsigned short* klh = (unsigned short*)(ws + O_KLP);
    unsigned short* kll = klh + 524288;

    float* qland = ws + O_QL;
    float* kland = ws + O_KL;
    float* attn2 = ws + O_A2;
    float* t1    = ws + O_T1;
    float* rs3   = ws + O_RS3;
    float* scal  = ws + O_SCAL;
    float* colsum= ws + O_CS;

    // pinv plane pool A: k-plane region (dead after attn3v)
    unsigned short* PBu  = (unsigned short*)(ws + O_KP);
    unsigned short* A2Ph = PBu + 0;
    unsigned short* A2Pl = PBu + 2097152;
    unsigned short* XZNh = PBu + 4194304;
    unsigned short* XZNl = PBu + 6291456;
    unsigned short* XZTh = PBu + 8388608;
    unsigned short* XZTl = PBu + 10485760;
    unsigned short* Y1Th = PBu + 12582912;
    unsigned short* Y1Tl = PBu + 14680064;
    // pinv plane pool B: X-plane region (dead after qkv)
    unsigned short* XRu  = (unsigned short*)(ws + O_XP);
    unsigned short* ZNah = XRu + 0;            // also hosts A2T (pre-iter2)
    unsigned short* ZNal = XRu + 2097152;
    unsigned short* ZNbh = XRu + 4194304;
    unsigned short* ZNbl = XRu + 6291456;
    unsigned short* ZTh_ = XRu + 8388608;
    unsigned short* ZTl_ = XRu + 10485760;
    unsigned short* Y2Th = XRu + 12582912;
    unsigned short* Y2Tl = XRu + 14680064;
    unsigned short* A2Th = ZNah;               // a2^T planes (z0 * denom)
    unsigned short* A2Tl = ZNal;
    // post-pinv aliases
    unsigned short* t2Th = (unsigned short*)(ws + O_QL);   // qland dead
    unsigned short* t2Tl = t2Th + 524288;
    unsigned short* OHh = PBu;                 // pool A dead after pinv
    unsigned short* OHl = PBu + 8388608;

    unsigned short* WQTh = (unsigned short*)(ws + O_WQT);
    unsigned short* WQTl = WQTh + 786432;
    unsigned short* WOTh = (unsigned short*)(ws + O_WOT);
    unsigned short* WOTl = WOTh + 262144;

    zero_f<<<2113, 256, 0, stream>>>(t1, 540688);   // t1+rs3+scal+colsum
    wtrans2<<<4096, 256, 0, stream>>>(w_qkv, w_out, WQTh, WQTl, WOTh, WOTl);
    xsplit<<<8192, 256, 0, stream>>>(x, Xh, Xl);

    mfma_qkv<<<dim3(12, 128), 256, 0, stream>>>(Xh, Xl, WQTh, WQTl,
                                                qh, ql, kh, kl, vTh, vTl);

    landmark_mean2<<<4096, 256, 0, stream>>>(qh, ql, kh, kl, qland, kland,
                                             qlh, qll, klh, kll);

    // F3 first: consumes k planes (pool A overwritten by softmax_fused next)
    attn3v_mfma<<<dim3(8, 4, 32), 256, 0, stream>>>(qlh, qll, kh, kl,
                                                    vTh, vTl, t1, rs3);

    gemm_a2<<<dim3(4, 4, 32), 256, 0, stream>>>(qland, kland, attn2);
    softmax_fused<<<8192, 256, 0, stream>>>(attn2, A2Ph, A2Pl, A2Th, A2Tl,
                                            colsum);
    scal_max<<<32, 256, 0, stream>>>(colsum, scal);

    // pinv: 6x4 all-plane stages (zinit folded into SC modes)
    unsigned short* ZNh[2] = {ZNah, ZNbh};
    unsigned short* ZNl[2] = {ZNal, ZNbl};
    int cur = 0;
    const dim3 pg(4, 4, 32);
    for (int it = 0; it < 6; ++it) {
        if (it == 0) {
            // xz = (1/denom) * (a2 @ a2^T)
            mfma_gemm_p<0, 1, true, true><<<pg, 256, 0, stream>>>(
                A2Ph, A2Pl, A2Ph, A2Pl, XZNh, XZNl, XZTh, XZTl,
                0.f, 0.f, scal);
        } else {
            mfma_gemm_p<0, 0, true, true><<<pg, 256, 0, stream>>>(
                A2Ph, A2Pl, ZTh_, ZTl_, XZNh, XZNl, XZTh, XZTl,
                1.f, 0.f, scal);
        }
        // Y1 = -xz@xz + 7*xz
        mfma_gemm_p<1, 0, false, true><<<pg, 256, 0, stream>>>(
            XZNh, XZNl, XZTh, XZTl, nullptr, nullptr, Y1Th, Y1Tl,
            -1.f, 7.f, scal);
        // Y2 = -xz@Y1 + 15*xz
        mfma_gemm_p<1, 0, false, true><<<pg, 256, 0, stream>>>(
            XZNh, XZNl, Y1Th, Y1Tl, nullptr, nullptr, Y2Th, Y2Tl,
            -1.f, 15.f, scal);
        // z' = -0.25*z@Y2 + 3.25*z
        if (it == 0) {
            // z = a2^T/denom: A = A2T, whole result scaled by 1/denom (SC=2)
            mfma_gemm_p<1, 2, true, true><<<pg, 256, 0, stream>>>(
                A2Th, A2Tl, Y2Th, Y2Tl, ZNbh, ZNbl, ZTh_, ZTl_,
                -0.25f, 3.25f, scal);
            cur = 1;
        } else {
            mfma_gemm_p<1, 0, true, true><<<pg, 256, 0, stream>>>(
                ZNh[cur], ZNl[cur], Y2Th, Y2Tl, ZNh[1 - cur], ZNl[1 - cur],
                ZTh_, ZTl_, -0.25f, 3.25f, scal);
            cur = 1 - cur;
        }
    }
    // zfin = ZN[0] (it1:->0, it2:->1, it3:->0, it4:->1, it5:->0)

    // t2 = zfin @ (t1 / rs3); t2^T planes into dead qland region
    t2_gemm<<<dim3(1, 4, 32), 256, 0, stream>>>(ZNh[0], ZNl[0], t1, rs3,
                                                t2Th, t2Tl);

    // F1 + conv fused -> OH planes (pool A, fully dead now)
    attn1t2_conv<<<dim3(64, 32), 256, 0, stream>>>(qh, ql, klh, kll,
                                                   t2Th, t2Tl, vTh, vTl,
                                                   w_res, OHh, OHl);

    mfma_final<<<dim3(4, 128), 256, 0, stream>>>(OHh, OHl, WOTh, WOTl, out);

    (void)in_sizes; (void)n_in; (void)out_size; (void)ws_size;
}

// Round 9
// 749.096 us; speedup vs baseline: 1.0479x; 1.0479x over previous
//
#include <hip/hip_runtime.h>

// ---------------------------------------------------------------------------
// Nystrom attention: split-bf16 (hi/lo, 3xMFMA) everywhere.
// R14: revert R13's Q-register experiment (regressed +14us: occupancy was
// not LDS-bound; scattered Q loads hurt). Attention kernels back to R12
// LDS-staged form. Added T5 s_setprio(1) around MFMA clusters in the two
// attn kernels (independent blocks at different phases = m191 regime).
// Plane GEMMs keep R12 2-phase dbuf global_load_lds.
// B=4, N=4096, DIM=512, H=8, DH=64, M=256, l=16, 6 pinv iters, conv K=33.
// ---------------------------------------------------------------------------

typedef __attribute__((ext_vector_type(8))) short bf16x8;
typedef __attribute__((ext_vector_type(4))) float f32x4;

// workspace layout (float units)
constexpr size_t O_XP  = 0;          // Xh/Xl planes; later pool B (ZN/ZT/Y2T, A2T)
constexpr size_t O_QP  = 8388608;    // q planes (hi/lo)
constexpr size_t O_KP  = 16777216;   // k planes; later pool A (A2P/XZN/XZT/Y1T); later OH planes
constexpr size_t O_VT  = 25165824;   // vT planes
constexpr size_t O_QL  = 33554432;   // qland fp32; later t2T planes
constexpr size_t O_KL  = 34078720;   // kland fp32
constexpr size_t O_QLP = 34603008;   // qland planes
constexpr size_t O_KLP = 35127296;   // kland planes
constexpr size_t O_A2  = 35651584;   // attn2 fp32 (pre-softmax scores)
constexpr size_t O_T1  = 37748736;
constexpr size_t O_RS3 = 38273024;
constexpr size_t O_SCAL= 38281216;
constexpr size_t O_CS  = 38281232;   // colsum [32][256]
constexpr size_t O_WQT = 38805520;
constexpr size_t O_WOT = 39591952;
constexpr size_t O_END = 39854096;   // ~159.4 MB

// ---------------------------------------------------------------------------
__device__ __forceinline__ void split2(float x, unsigned short& h,
                                       unsigned short& l) {
    unsigned u  = __float_as_uint(x);
    unsigned hb = (u + 0x7FFFu + ((u >> 16) & 1u)) & 0xFFFF0000u;  // RNE hi
    h = (unsigned short)(hb >> 16);
    float d = x - __uint_as_float(hb);
    l = (unsigned short)(__float_as_uint(d) >> 16);
}

__device__ __forceinline__ float b2f(unsigned short s) {
    return __uint_as_float((unsigned)s << 16);
}

__device__ __forceinline__ f32x4 mfma3(bf16x8 ah, bf16x8 al, bf16x8 bh,
                                       bf16x8 bl, f32x4 c) {
    c = __builtin_amdgcn_mfma_f32_16x16x32_bf16(ah, bh, c, 0, 0, 0);
    c = __builtin_amdgcn_mfma_f32_16x16x32_bf16(ah, bl, c, 0, 0, 0);
    c = __builtin_amdgcn_mfma_f32_16x16x32_bf16(al, bh, c, 0, 0, 0);
    return c;
}

// async global->LDS, 16 B per lane (gfx950). LDS dest = uniform base + lane*16.
__device__ __forceinline__ void g2l16(const unsigned short* g,
                                      unsigned short* l) {
    __builtin_amdgcn_global_load_lds(
        (const __attribute__((address_space(1))) void*)g,
        (__attribute__((address_space(3))) void*)l, 16, 0, 0);
}

// split a float4 into hi/lo planes, write packed uint2 at H[off], L[off]
__device__ __forceinline__ void stage_split4(float4 av, unsigned short* H,
                                             unsigned short* L, int off) {
    unsigned short h0, h1, h2, h3, l0, l1, l2, l3;
    split2(av.x, h0, l0); split2(av.y, h1, l1);
    split2(av.z, h2, l2); split2(av.w, h3, l3);
    uint2 ph, pl;
    ph.x = (unsigned)h0 | ((unsigned)h1 << 16);
    ph.y = (unsigned)h2 | ((unsigned)h3 << 16);
    pl.x = (unsigned)l0 | ((unsigned)l1 << 16);
    pl.y = (unsigned)l2 | ((unsigned)l3 << 16);
    *(uint2*)&H[off] = ph;
    *(uint2*)&L[off] = pl;
}

// ---------------------------------------------------------------------------
// X -> split planes (one-time)
// ---------------------------------------------------------------------------
__global__ void xsplit(const float* __restrict__ X,
                       unsigned short* __restrict__ Xh,
                       unsigned short* __restrict__ Xl) {
    int idx = blockIdx.x * 256 + threadIdx.x;
    float4 v = *(const float4*)(X + (size_t)idx * 4);
    stage_split4(v, Xh, Xl, idx * 4);
}

// ---------------------------------------------------------------------------
// both weight transposes in one dispatch. grid 4096.
// ---------------------------------------------------------------------------
__global__ void wtrans2(const float* __restrict__ Wq,
                        const float* __restrict__ Wo,
                        unsigned short* __restrict__ QTh,
                        unsigned short* __restrict__ QTl,
                        unsigned short* __restrict__ OTh,
                        unsigned short* __restrict__ OTl) {
    int idx = blockIdx.x * 256 + threadIdx.x;
    unsigned short h, l;
    if (idx < 786432) {
        int n = idx >> 9, kk = idx & 511;
        split2(Wq[(size_t)kk * 1536 + n], h, l);
        QTh[idx] = h;
        QTl[idx] = l;
    } else {
        int j = idx - 786432;
        int n = j >> 9, kk = j & 511;
        split2(Wo[(size_t)kk * 512 + n], h, l);
        OTh[j] = h;
        OTl[j] = l;
    }
}

// ---------------------------------------------------------------------------
// All-plane pinv GEMM stage: C = alpha*(A@B) + beta*A_elem.
// SC=0: as-is. SC=1: alpha := 1/denom (EPI=0). SC=2: whole result *= 1/denom.
// A = normal planes AN[m][k]; B = transposed planes BT[n][k].
// 2-phase double-buffered global_load_lds staging. grid (4,4,32), 256 thr.
// ---------------------------------------------------------------------------
template <int EPI, int SC, bool WN, bool WTT>
__global__ __launch_bounds__(256) void mfma_gemm_p(
    const unsigned short* __restrict__ ANh, const unsigned short* __restrict__ ANl,
    const unsigned short* __restrict__ BTh, const unsigned short* __restrict__ BTl,
    unsigned short* __restrict__ CNh, unsigned short* __restrict__ CNl,
    unsigned short* __restrict__ CTh, unsigned short* __restrict__ CTl,
    float alpha, float beta, const float* __restrict__ scal) {
    __shared__ __align__(16) unsigned short Ah[2][2048], Al[2][2048];
    __shared__ __align__(16) unsigned short Bh[2][2048], Bl[2][2048];
    const int t = threadIdx.x;
    const int wave = t >> 6, lane = t & 63, lm = lane & 15, lq = lane >> 4;
    const int z = blockIdx.z;
    const int m0 = blockIdx.y * 64, n0 = blockIdx.x * 64;
    const size_t zo = (size_t)z * 65536;

    // staging role: wave 0->Ah, 1->Al, 2->Bh, 3->Bl
    const unsigned short* gsrc;
    unsigned short (*ldst)[2048];
    if (wave == 0)      { gsrc = ANh + zo + (size_t)m0 * 256; ldst = Ah; }
    else if (wave == 1) { gsrc = ANl + zo + (size_t)m0 * 256; ldst = Al; }
    else if (wave == 2) { gsrc = BTh + zo + (size_t)n0 * 256; ldst = Bh; }
    else                { gsrc = BTl + zo + (size_t)n0 * 256; ldst = Bl; }
    const int srow = lane >> 2, sko = (lane & 3) * 8;

    auto stage = [&](int b, int kt) {
#pragma unroll
        for (int c = 0; c < 4; ++c)
            g2l16(gsrc + (size_t)(c * 16 + srow) * 256 + kt + sko,
                  &ldst[b][c * 512]);
    };

    f32x4 acc[4];
#pragma unroll
    for (int j = 0; j < 4; ++j) acc[j] = (f32x4){0.f, 0.f, 0.f, 0.f};

    stage(0, 0);
    __syncthreads();
    int cur = 0;
    for (int kt = 0; kt < 256; kt += 32) {
        if (kt + 32 < 256) stage(cur ^ 1, kt + 32);
        bf16x8 ah = *(const bf16x8*)&Ah[cur][(wave * 16 + lm) * 32 + lq * 8];
        bf16x8 al = *(const bf16x8*)&Al[cur][(wave * 16 + lm) * 32 + lq * 8];
#pragma unroll
        for (int j = 0; j < 4; ++j) {
            bf16x8 bh = *(const bf16x8*)&Bh[cur][(j * 16 + lm) * 32 + lq * 8];
            bf16x8 bl = *(const bf16x8*)&Bl[cur][(j * 16 + lm) * 32 + lq * 8];
            acc[j] = mfma3(ah, al, bh, bl, acc[j]);
        }
        __syncthreads();
        cur ^= 1;
    }

    const float scv = (SC != 0) ? 1.0f / (scal[0] + 1e-8f) : 1.0f;
    const float a = (SC == 1) ? scv : alpha;
    const int r0 = m0 + wave * 16 + lq * 4;
#pragma unroll
    for (int j = 0; j < 4; ++j) {
        int c = n0 + j * 16 + lm;
        float vals[4];
#pragma unroll
        for (int e = 0; e < 4; ++e) {
            float v = a * acc[j][e];
            if (EPI == 1) {
                size_t ao = zo + (size_t)(r0 + e) * 256 + c;
                v += beta * (b2f(ANh[ao]) + b2f(ANl[ao]));
            }
            if (SC == 2) v *= scv;
            vals[e] = v;
        }
        unsigned short hh[4], ll[4];
#pragma unroll
        for (int e = 0; e < 4; ++e) split2(vals[e], hh[e], ll[e]);
        if (WN) {
#pragma unroll
            for (int e = 0; e < 4; ++e) {
                size_t o = zo + (size_t)(r0 + e) * 256 + c;
                CNh[o] = hh[e];
                CNl[o] = ll[e];
            }
        }
        if (WTT) {
            uint2 ph, pl;
            ph.x = (unsigned)hh[0] | ((unsigned)hh[1] << 16);
            ph.y = (unsigned)hh[2] | ((unsigned)hh[3] << 16);
            pl.x = (unsigned)ll[0] | ((unsigned)ll[1] << 16);
            pl.y = (unsigned)ll[2] | ((unsigned)ll[3] << 16);
            *(uint2*)&CTh[zo + (size_t)c * 256 + r0] = ph;
            *(uint2*)&CTl[zo + (size_t)c * 256 + r0] = pl;
        }
    }
}

// fp32 64x64 micro-kernel
__device__ __forceinline__ void mt16(const float* As, const float* Bs,
                                     int ty4, int tx4, float (&acc)[4][4]) {
#pragma unroll
    for (int kk = 0; kk < 16; ++kk) {
        float4 a4 = *(const float4*)(As + kk * 68 + ty4);
        float4 b4 = *(const float4*)(Bs + kk * 68 + tx4);
        float aa[4] = {a4.x, a4.y, a4.z, a4.w};
        float bb[4] = {b4.x, b4.y, b4.z, b4.w};
#pragma unroll
        for (int u = 0; u < 4; ++u)
#pragma unroll
            for (int w = 0; w < 4; ++w)
                acc[u][w] += aa[u] * bb[w];
    }
}

// ---------------------------------------------------------------------------
// t2 = z6 @ (t1/rs3): A from ZN planes (h+l recombine). grid (1,4,32).
// Emits t2^T planes only (stride 16384/z).
// ---------------------------------------------------------------------------
__global__ __launch_bounds__(256) void t2_gemm(
    const unsigned short* __restrict__ ANh, const unsigned short* __restrict__ ANl,
    const float* __restrict__ t1, const float* __restrict__ rs3,
    unsigned short* __restrict__ t2Th, unsigned short* __restrict__ t2Tl) {
    __shared__ float As[16 * 68];
    __shared__ float Bs[16 * 68];
    const int t  = threadIdx.x;
    const int z  = blockIdx.z;
    const int m0 = blockIdx.y * 64;
    const size_t zo = (size_t)z * 65536;
    const float* Bb = t1 + (size_t)z * 16384;
    const int tx4 = (t & 15) * 4;
    const int ty4 = (t >> 4) * 4;
    const int ar  = t >> 2, ak = (t & 3) * 4;
    const int bkr = t >> 4, bc4 = (t & 15) * 4;
    float acc[4][4] = {};
    for (int kt = 0; kt < 256; kt += 16) {
        uint2 h2 = *(const uint2*)(ANh + zo + (size_t)(m0 + ar) * 256 + kt + ak);
        uint2 l2 = *(const uint2*)(ANl + zo + (size_t)(m0 + ar) * 256 + kt + ak);
        const unsigned short* hp = (const unsigned short*)&h2;
        const unsigned short* lp = (const unsigned short*)&l2;
        float4 av = make_float4(b2f(hp[0]) + b2f(lp[0]), b2f(hp[1]) + b2f(lp[1]),
                                b2f(hp[2]) + b2f(lp[2]), b2f(hp[3]) + b2f(lp[3]));
        float4 bv = *(const float4*)(Bb + (size_t)(kt + bkr) * 64 + bc4);
        float rr = 1.0f / rs3[z * 256 + kt + bkr];
        bv.x *= rr; bv.y *= rr; bv.z *= rr; bv.w *= rr;
        As[(ak + 0) * 68 + ar] = av.x;
        As[(ak + 1) * 68 + ar] = av.y;
        As[(ak + 2) * 68 + ar] = av.z;
        As[(ak + 3) * 68 + ar] = av.w;
        *(float4*)(Bs + bkr * 68 + bc4) = bv;
        __syncthreads();
        mt16(As, Bs, ty4, tx4, acc);
        __syncthreads();
    }
#pragma unroll
    for (int w = 0; w < 4; ++w) {
        unsigned short hh[4], ll[4];
#pragma unroll
        for (int u = 0; u < 4; ++u) split2(acc[u][w], hh[u], ll[u]);
        uint2 ph, pl;
        ph.x = (unsigned)hh[0] | ((unsigned)hh[1] << 16);
        ph.y = (unsigned)hh[2] | ((unsigned)hh[3] << 16);
        pl.x = (unsigned)ll[0] | ((unsigned)ll[1] << 16);
        pl.y = (unsigned)ll[2] | ((unsigned)ll[3] << 16);
        size_t off = (size_t)z * 16384 + (size_t)(tx4 + w) * 256 + m0 + ty4;
        *(uint2*)&t2Th[off] = ph;
        *(uint2*)&t2Tl[off] = pl;
    }
}

// ---------------------------------------------------------------------------
// qkv MFMA GEMM: X planes [16384,512] @ w_qkv planes; emits q/k planes
// ([bh][n][d], q scaled 0.125) and vT planes [bh][dh][4096]. grid (12,128).
// 2-phase double-buffered global_load_lds staging.
// ---------------------------------------------------------------------------
__global__ __launch_bounds__(256) void mfma_qkv(
    const unsigned short* __restrict__ Xh_, const unsigned short* __restrict__ Xl_,
    const unsigned short* __restrict__ WTh, const unsigned short* __restrict__ WTl,
    unsigned short* __restrict__ qh, unsigned short* __restrict__ ql,
    unsigned short* __restrict__ kh, unsigned short* __restrict__ kl,
    unsigned short* __restrict__ vTh, unsigned short* __restrict__ vTl) {
    __shared__ __align__(16) unsigned short Ah[2][4096], Al[2][4096];
    __shared__ __align__(16) unsigned short Bh[2][4096], Bl[2][4096];
    const int t = threadIdx.x;
    const int wave = t >> 6, lane = t & 63, lm = lane & 15, lq = lane >> 4;
    // XCD-aware bijective swizzle: nwg=1536, 1536/8=192 per XCD
    int orig = blockIdx.y * 12 + blockIdx.x;
    int wg = (orig & 7) * 192 + (orig >> 3);
    const int m0 = (wg / 12) * 128, n0 = (wg % 12) * 128;
    const int mb = (wave >> 1) * 64, nb = (wave & 1) * 64;

    // staging role
    const unsigned short* gsrc;
    unsigned short (*ldst)[4096];
    if (wave == 0)      { gsrc = Xh_ + (size_t)m0 * 512; ldst = Ah; }
    else if (wave == 1) { gsrc = Xl_ + (size_t)m0 * 512; ldst = Al; }
    else if (wave == 2) { gsrc = WTh + (size_t)n0 * 512; ldst = Bh; }
    else                { gsrc = WTl + (size_t)n0 * 512; ldst = Bl; }
    const int srow = lane >> 2, sko = (lane & 3) * 8;

    auto stage = [&](int b, int kt) {
#pragma unroll
        for (int c = 0; c < 8; ++c)
            g2l16(gsrc + (size_t)(c * 16 + srow) * 512 + kt + sko,
                  &ldst[b][c * 512]);
    };

    f32x4 acc[4][4];
#pragma unroll
    for (int i = 0; i < 4; ++i)
#pragma unroll
        for (int j = 0; j < 4; ++j) acc[i][j] = (f32x4){0.f, 0.f, 0.f, 0.f};

    stage(0, 0);
    __syncthreads();
    int cur = 0;
    for (int kt = 0; kt < 512; kt += 32) {
        if (kt + 32 < 512) stage(cur ^ 1, kt + 32);
        bf16x8 ah[4], al[4], bh[4], bl[4];
#pragma unroll
        for (int i = 0; i < 4; ++i) {
            ah[i] = *(const bf16x8*)&Ah[cur][(mb + i * 16 + lm) * 32 + lq * 8];
            al[i] = *(const bf16x8*)&Al[cur][(mb + i * 16 + lm) * 32 + lq * 8];
        }
#pragma unroll
        for (int j = 0; j < 4; ++j) {
            bh[j] = *(const bf16x8*)&Bh[cur][(nb + j * 16 + lm) * 32 + lq * 8];
            bl[j] = *(const bf16x8*)&Bl[cur][(nb + j * 16 + lm) * 32 + lq * 8];
        }
#pragma unroll
        for (int i = 0; i < 4; ++i)
#pragma unroll
            for (int j = 0; j < 4; ++j)
                acc[i][j] = mfma3(ah[i], al[i], bh[j], bl[j], acc[i][j]);
        __syncthreads();
        cur ^= 1;
    }
#pragma unroll
    for (int i = 0; i < 4; ++i)
#pragma unroll
        for (int j = 0; j < 4; ++j) {
            int r0 = m0 + mb + i * 16 + lq * 4;
            int c  = n0 + nb + j * 16 + lm;
            int which = c >> 9, h = (c >> 6) & 7, d = c & 63;
            int b = r0 >> 12, nbase = r0 & 4095;
            if (which == 2) {
                unsigned short hh[4], ll[4];
#pragma unroll
                for (int e = 0; e < 4; ++e) split2(acc[i][j][e], hh[e], ll[e]);
                uint2 ph, pl;
                ph.x = (unsigned)hh[0] | ((unsigned)hh[1] << 16);
                ph.y = (unsigned)hh[2] | ((unsigned)hh[3] << 16);
                pl.x = (unsigned)ll[0] | ((unsigned)ll[1] << 16);
                pl.y = (unsigned)ll[2] | ((unsigned)ll[3] << 16);
                size_t off = ((size_t)(b * 8 + h) * 64 + d) * 4096 + nbase;
                *(uint2*)&vTh[off] = ph;
                *(uint2*)&vTl[off] = pl;
            } else {
                unsigned short* Ph = which ? kh : qh;
                unsigned short* Pl = which ? kl : ql;
                float sc = which ? 1.0f : 0.125f;
#pragma unroll
                for (int e = 0; e < 4; ++e) {
                    unsigned short hh, ll;
                    split2(acc[i][j][e] * sc, hh, ll);
                    size_t off = (size_t)(b * 8 + h) * 262144 +
                                 (size_t)(nbase + e) * 64 + d;
                    Ph[off] = hh;
                    Pl[off] = ll;
                }
            }
        }
}

// ---------------------------------------------------------------------------
// final MFMA GEMM: out[16384,512] = OH planes (gathered) @ w_out planes.
// grid (4,128). 2-phase double-buffered global_load_lds (A via gather).
// ---------------------------------------------------------------------------
__global__ __launch_bounds__(256) void mfma_final(
    const unsigned short* __restrict__ OHh, const unsigned short* __restrict__ OHl,
    const unsigned short* __restrict__ WTh, const unsigned short* __restrict__ WTl,
    float* __restrict__ out) {
    __shared__ __align__(16) unsigned short Ah[2][4096], Al[2][4096];
    __shared__ __align__(16) unsigned short Bh[2][4096], Bl[2][4096];
    const int t = threadIdx.x;
    const int wave = t >> 6, lane = t & 63, lm = lane & 15, lq = lane >> 4;
    // XCD-aware bijective swizzle: nwg=512, 512/8=64 per XCD
    int orig = blockIdx.y * 4 + blockIdx.x;
    int wg = (orig & 7) * 64 + (orig >> 3);
    const int m0 = (wg >> 2) * 128, n0 = (wg & 3) * 128;
    const int mb = (wave >> 1) * 64, nb = (wave & 1) * 64;

    const bool isA = wave < 2;
    const unsigned short* gA = (wave == 0) ? OHh : OHl;
    const unsigned short* gB = (wave == 2) ? WTh : WTl;
    unsigned short (*ldst)[4096] = (wave == 0) ? Ah : (wave == 1) ? Al
                                 : (wave == 2) ? Bh : Bl;
    const int srow = lane >> 2, sko = (lane & 3) * 8;
    // A-gather constants per chunk
    int gb[8], gn[8];
#pragma unroll
    for (int c = 0; c < 8; ++c) {
        int gr = m0 + c * 16 + srow;
        gb[c] = gr >> 12;
        gn[c] = gr & 4095;
    }

    auto stage = [&](int b, int kt) {
        if (isA) {
            int kk = kt + sko;
            size_t koff = (size_t)(kk >> 6) * 262144 + (kk & 63);
#pragma unroll
            for (int c = 0; c < 8; ++c)
                g2l16(gA + (size_t)gb[c] * 2097152 + koff +
                          (size_t)gn[c] * 64,
                      &ldst[b][c * 512]);
        } else {
#pragma unroll
            for (int c = 0; c < 8; ++c)
                g2l16(gB + (size_t)(n0 + c * 16 + srow) * 512 + kt + sko,
                      &ldst[b][c * 512]);
        }
    };

    f32x4 acc[4][4];
#pragma unroll
    for (int i = 0; i < 4; ++i)
#pragma unroll
        for (int j = 0; j < 4; ++j) acc[i][j] = (f32x4){0.f, 0.f, 0.f, 0.f};

    stage(0, 0);
    __syncthreads();
    int cur = 0;
    for (int kt = 0; kt < 512; kt += 32) {
        if (kt + 32 < 512) stage(cur ^ 1, kt + 32);
        bf16x8 ah[4], al[4], bh[4], bl[4];
#pragma unroll
        for (int i = 0; i < 4; ++i) {
            ah[i] = *(const bf16x8*)&Ah[cur][(mb + i * 16 + lm) * 32 + lq * 8];
            al[i] = *(const bf16x8*)&Al[cur][(mb + i * 16 + lm) * 32 + lq * 8];
        }
#pragma unroll
        for (int j = 0; j < 4; ++j) {
            bh[j] = *(const bf16x8*)&Bh[cur][(nb + j * 16 + lm) * 32 + lq * 8];
            bl[j] = *(const bf16x8*)&Bl[cur][(nb + j * 16 + lm) * 32 + lq * 8];
        }
#pragma unroll
        for (int i = 0; i < 4; ++i)
#pragma unroll
            for (int j = 0; j < 4; ++j)
                acc[i][j] = mfma3(ah[i], al[i], bh[j], bl[j], acc[i][j]);
        __syncthreads();
        cur ^= 1;
    }
#pragma unroll
    for (int i = 0; i < 4; ++i)
#pragma unroll
        for (int j = 0; j < 4; ++j) {
            int r0 = m0 + mb + i * 16 + lq * 4;
            int c  = n0 + nb + j * 16 + lm;
#pragma unroll
            for (int e = 0; e < 4; ++e)
                out[(size_t)(r0 + e) * 512 + c] = acc[i][j][e];
        }
}

// ---------------------------------------------------------------------------
// F3 MFMA: t1 += exp(qland@k^T)@v, rs3 += rowsums. grid (8, 4, 32).
// R12 LDS-staged form + T5 setprio around MFMA clusters.
// ---------------------------------------------------------------------------
__global__ __launch_bounds__(256) void attn3v_mfma(
    const unsigned short* __restrict__ qlh, const unsigned short* __restrict__ qll,
    const unsigned short* __restrict__ kh_, const unsigned short* __restrict__ kl_,
    const unsigned short* __restrict__ vTh, const unsigned short* __restrict__ vTl,
    float* __restrict__ t1, float* __restrict__ rs3) {
    __shared__ unsigned short Qh[4608], Ql[4608];
    __shared__ unsigned short Kh[4608], Kl[4608];
    __shared__ unsigned short Eh[4608], El[4608];
    const int t = threadIdx.x;
    const int wave = t >> 6, lane = t & 63, lm = lane & 15, lq = lane >> 4;
    const int bz = blockIdx.z, m0 = blockIdx.y * 64, c0 = blockIdx.x * 8;
    const unsigned short* qhb = qlh + (size_t)bz * 16384;
    const unsigned short* qlb = qll + (size_t)bz * 16384;
    const unsigned short* khb = kh_ + (size_t)bz * 262144;
    const unsigned short* klb = kl_ + (size_t)bz * 262144;
    const unsigned short* vhb = vTh + (size_t)bz * 262144;
    const unsigned short* vlb = vTl + (size_t)bz * 262144;
#pragma unroll
    for (int r = 0; r < 2; ++r) {
        int id = t + r * 256, row = id >> 3, ko = (id & 7) * 8;
        *(uint4*)&Qh[row * 72 + ko] =
            *(const uint4*)(qhb + (size_t)(m0 + row) * 64 + ko);
        *(uint4*)&Ql[row * 72 + ko] =
            *(const uint4*)(qlb + (size_t)(m0 + row) * 64 + ko);
    }
    f32x4 acc[4];
#pragma unroll
    for (int j = 0; j < 4; ++j) acc[j] = (f32x4){0.f, 0.f, 0.f, 0.f};
    float rsum[4] = {0.f, 0.f, 0.f, 0.f};
    __syncthreads();

    for (int c = c0; c < c0 + 8; ++c) {
        const int tok0 = c * 64;
#pragma unroll
        for (int r = 0; r < 2; ++r) {
            int id = t + r * 256, row = id >> 3, ko = (id & 7) * 8;
            *(uint4*)&Kh[row * 72 + ko] =
                *(const uint4*)(khb + (size_t)(tok0 + row) * 64 + ko);
            *(uint4*)&Kl[row * 72 + ko] =
                *(const uint4*)(klb + (size_t)(tok0 + row) * 64 + ko);
        }
        __syncthreads();
        bf16x8 a0  = *(const bf16x8*)&Qh[(wave * 16 + lm) * 72 + lq * 8];
        bf16x8 a0l = *(const bf16x8*)&Ql[(wave * 16 + lm) * 72 + lq * 8];
        bf16x8 a1  = *(const bf16x8*)&Qh[(wave * 16 + lm) * 72 + 32 + lq * 8];
        bf16x8 a1l = *(const bf16x8*)&Ql[(wave * 16 + lm) * 72 + 32 + lq * 8];
        f32x4 s[4];
#pragma unroll
        for (int j = 0; j < 4; ++j) s[j] = (f32x4){0.f, 0.f, 0.f, 0.f};
        __builtin_amdgcn_s_setprio(1);
#pragma unroll
        for (int j = 0; j < 4; ++j) {
            bf16x8 b0  = *(const bf16x8*)&Kh[(j * 16 + lm) * 72 + lq * 8];
            bf16x8 b0l = *(const bf16x8*)&Kl[(j * 16 + lm) * 72 + lq * 8];
            bf16x8 b1  = *(const bf16x8*)&Kh[(j * 16 + lm) * 72 + 32 + lq * 8];
            bf16x8 b1l = *(const bf16x8*)&Kl[(j * 16 + lm) * 72 + 32 + lq * 8];
            s[j] = mfma3(a0, a0l, b0, b0l, s[j]);
            s[j] = mfma3(a1, a1l, b1, b1l, s[j]);
        }
        __builtin_amdgcn_s_setprio(0);
        __syncthreads();
#pragma unroll
        for (int j = 0; j < 4; ++j)
#pragma unroll
            for (int e = 0; e < 4; ++e) {
                float ev = __expf(s[j][e]);
                rsum[e] += ev;
                unsigned short h, l;
                split2(ev, h, l);
                int off = (wave * 16 + lq * 4 + e) * 72 + j * 16 + lm;
                Eh[off] = h;
                El[off] = l;
            }
#pragma unroll
        for (int r = 0; r < 2; ++r) {
            int id = t + r * 256, dh = id >> 3, t8 = (id & 7) * 8;
            *(uint4*)&Kh[dh * 72 + t8] =
                *(const uint4*)(vhb + (size_t)dh * 4096 + tok0 + t8);
            *(uint4*)&Kl[dh * 72 + t8] =
                *(const uint4*)(vlb + (size_t)dh * 4096 + tok0 + t8);
        }
        __syncthreads();
        bf16x8 e0  = *(const bf16x8*)&Eh[(wave * 16 + lm) * 72 + lq * 8];
        bf16x8 e0l = *(const bf16x8*)&El[(wave * 16 + lm) * 72 + lq * 8];
        bf16x8 e1  = *(const bf16x8*)&Eh[(wave * 16 + lm) * 72 + 32 + lq * 8];
        bf16x8 e1l = *(const bf16x8*)&El[(wave * 16 + lm) * 72 + 32 + lq * 8];
        __builtin_amdgcn_s_setprio(1);
#pragma unroll
        for (int j = 0; j < 4; ++j) {
            bf16x8 v0  = *(const bf16x8*)&Kh[(j * 16 + lm) * 72 + lq * 8];
            bf16x8 v0l = *(const bf16x8*)&Kl[(j * 16 + lm) * 72 + lq * 8];
            bf16x8 v1  = *(const bf16x8*)&Kh[(j * 16 + lm) * 72 + 32 + lq * 8];
            bf16x8 v1l = *(const bf16x8*)&Kl[(j * 16 + lm) * 72 + 32 + lq * 8];
            acc[j] = mfma3(e0, e0l, v0, v0l, acc[j]);
            acc[j] = mfma3(e1, e1l, v1, v1l, acc[j]);
        }
        __builtin_amdgcn_s_setprio(0);
        __syncthreads();
    }
    float* t1b = t1 + (size_t)bz * 16384;
#pragma unroll
    for (int j = 0; j < 4; ++j)
#pragma unroll
        for (int e = 0; e < 4; ++e)
            atomicAdd(t1b + (size_t)(m0 + wave * 16 + lq * 4 + e) * 64 +
                          j * 16 + lm,
                      acc[j][e]);
#pragma unroll
    for (int e = 0; e < 4; ++e) {
        float vs = rsum[e];
        for (int mm = 1; mm < 16; mm <<= 1) vs += __shfl_xor(vs, mm);
        if (lm == 0)
            atomicAdd(rs3 + bz * 256 + m0 + wave * 16 + lq * 4 + e, vs);
    }
}

// ---------------------------------------------------------------------------
// F1 MFMA + fused depthwise conv: OH planes = softmax(q@kland^T)@t2 + conv(v).
// R12 LDS-staged form + T5 setprio around MFMA clusters. grid (64, 32).
// ---------------------------------------------------------------------------
__global__ __launch_bounds__(256) void attn1t2_conv(
    const unsigned short* __restrict__ qh_, const unsigned short* __restrict__ ql_,
    const unsigned short* __restrict__ klh, const unsigned short* __restrict__ kll,
    const unsigned short* __restrict__ t2Th, const unsigned short* __restrict__ t2Tl,
    const unsigned short* __restrict__ vTh, const unsigned short* __restrict__ vTl,
    const float* __restrict__ wres,
    unsigned short* __restrict__ OHh, unsigned short* __restrict__ OHl) {
    __shared__ __align__(16) unsigned short SH[27648];   // 55296 B
    unsigned short* Qh = SH;
    unsigned short* Ql = SH + 4608;
    unsigned short* Kh = SH + 9216;
    unsigned short* Kl = SH + 13824;
    unsigned short* Eh = SH + 18432;
    unsigned short* El = SH + 23040;
    __shared__ float Ws[33];
    const int t = threadIdx.x;
    const int wave = t >> 6, lane = t & 63, lm = lane & 15, lq = lane >> 4;
    const int bz = blockIdx.y, m0 = blockIdx.x * 64;
    if (t < 33) Ws[t] = wres[(bz & 7) * 33 + t];
    const unsigned short* qhb = qh_ + (size_t)bz * 262144;
    const unsigned short* qlb = ql_ + (size_t)bz * 262144;
    const unsigned short* khb = klh + (size_t)bz * 16384;
    const unsigned short* klb = kll + (size_t)bz * 16384;
    const unsigned short* t2h = t2Th + (size_t)bz * 16384;
    const unsigned short* t2l = t2Tl + (size_t)bz * 16384;
#pragma unroll
    for (int r = 0; r < 2; ++r) {
        int id = t + r * 256, row = id >> 3, ko = (id & 7) * 8;
        *(uint4*)&Qh[row * 72 + ko] =
            *(const uint4*)(qhb + (size_t)(m0 + row) * 64 + ko);
        *(uint4*)&Ql[row * 72 + ko] =
            *(const uint4*)(qlb + (size_t)(m0 + row) * 64 + ko);
    }
    f32x4 acc[4];
#pragma unroll
    for (int j = 0; j < 4; ++j) acc[j] = (f32x4){0.f, 0.f, 0.f, 0.f};
    float rsum[4] = {0.f, 0.f, 0.f, 0.f};
    __syncthreads();

    for (int lc = 0; lc < 4; ++lc) {
        const int l0 = lc * 64;
#pragma unroll
        for (int r = 0; r < 2; ++r) {
            int id = t + r * 256, row = id >> 3, ko = (id & 7) * 8;
            *(uint4*)&Kh[row * 72 + ko] =
                *(const uint4*)(khb + (size_t)(l0 + row) * 64 + ko);
            *(uint4*)&Kl[row * 72 + ko] =
                *(const uint4*)(klb + (size_t)(l0 + row) * 64 + ko);
        }
        __syncthreads();
        bf16x8 a0  = *(const bf16x8*)&Qh[(wave * 16 + lm) * 72 + lq * 8];
        bf16x8 a0l = *(const bf16x8*)&Ql[(wave * 16 + lm) * 72 + lq * 8];
        bf16x8 a1  = *(const bf16x8*)&Qh[(wave * 16 + lm) * 72 + 32 + lq * 8];
        bf16x8 a1l = *(const bf16x8*)&Ql[(wave * 16 + lm) * 72 + 32 + lq * 8];
        f32x4 s[4];
#pragma unroll
        for (int j = 0; j < 4; ++j) s[j] = (f32x4){0.f, 0.f, 0.f, 0.f};
        __builtin_amdgcn_s_setprio(1);
#pragma unroll
        for (int j = 0; j < 4; ++j) {
            bf16x8 b0  = *(const bf16x8*)&Kh[(j * 16 + lm) * 72 + lq * 8];
            bf16x8 b0l = *(const bf16x8*)&Kl[(j * 16 + lm) * 72 + lq * 8];
            bf16x8 b1  = *(const bf16x8*)&Kh[(j * 16 + lm) * 72 + 32 + lq * 8];
            bf16x8 b1l = *(const bf16x8*)&Kl[(j * 16 + lm) * 72 + 32 + lq * 8];
            s[j] = mfma3(a0, a0l, b0, b0l, s[j]);
            s[j] = mfma3(a1, a1l, b1, b1l, s[j]);
        }
        __builtin_amdgcn_s_setprio(0);
        __syncthreads();
#pragma unroll
        for (int j = 0; j < 4; ++j)
#pragma unroll
            for (int e = 0; e < 4; ++e) {
                float ev = __expf(s[j][e]);
                rsum[e] += ev;
                unsigned short h, l;
                split2(ev, h, l);
                int off = (wave * 16 + lq * 4 + e) * 72 + j * 16 + lm;
                Eh[off] = h;
                El[off] = l;
            }
#pragma unroll
        for (int r = 0; r < 2; ++r) {
            int id = t + r * 256, dh = id >> 3, t8 = (id & 7) * 8;
            *(uint4*)&Kh[dh * 72 + t8] =
                *(const uint4*)(t2h + (size_t)dh * 256 + l0 + t8);
            *(uint4*)&Kl[dh * 72 + t8] =
                *(const uint4*)(t2l + (size_t)dh * 256 + l0 + t8);
        }
        __syncthreads();
        bf16x8 e0  = *(const bf16x8*)&Eh[(wave * 16 + lm) * 72 + lq * 8];
        bf16x8 e0l = *(const bf16x8*)&El[(wave * 16 + lm) * 72 + lq * 8];
        bf16x8 e1  = *(const bf16x8*)&Eh[(wave * 16 + lm) * 72 + 32 + lq * 8];
        bf16x8 e1l = *(const bf16x8*)&El[(wave * 16 + lm) * 72 + 32 + lq * 8];
        __builtin_amdgcn_s_setprio(1);
#pragma unroll
        for (int j = 0; j < 4; ++j) {
            bf16x8 v0  = *(const bf16x8*)&Kh[(j * 16 + lm) * 72 + lq * 8];
            bf16x8 v0l = *(const bf16x8*)&Kl[(j * 16 + lm) * 72 + lq * 8];
            bf16x8 v1  = *(const bf16x8*)&Kh[(j * 16 + lm) * 72 + 32 + lq * 8];
            bf16x8 v1l = *(const bf16x8*)&Kl[(j * 16 + lm) * 72 + 32 + lq * 8];
            acc[j] = mfma3(e0, e0l, v0, v0l, acc[j]);
            acc[j] = mfma3(e1, e1l, v1, v1l, acc[j]);
        }
        __builtin_amdgcn_s_setprio(0);
        __syncthreads();
    }
    float rinv[4];
#pragma unroll
    for (int e = 0; e < 4; ++e) {
        float vs = rsum[e];
        for (int mm = 1; mm < 16; mm <<= 1) vs += __shfl_xor(vs, mm);
        rinv[e] = 1.0f / vs;
    }

    // ---- fused conv: stage v window [m0-16, m0+80) into dead Q/K LDS ----
    __syncthreads();
    float* Vs = (float*)SH;                      // 96 x 65 fp32 = 24960 B
    const unsigned short* vhb = vTh + (size_t)bz * 262144;
    const unsigned short* vlb = vTl + (size_t)bz * 262144;
#pragma unroll
    for (int r = 0; r < 3; ++r) {
        int id = t + r * 256;                    // 0..767 = 64 dh x 12 chunks
        int d = id / 12, ch = id - d * 12;
        int n = m0 - 16 + ch * 8;
        uint4 h4 = make_uint4(0u, 0u, 0u, 0u);
        uint4 l4 = make_uint4(0u, 0u, 0u, 0u);
        if ((unsigned)n < 4096u) {
            h4 = *(const uint4*)(vhb + (size_t)d * 4096 + n);
            l4 = *(const uint4*)(vlb + (size_t)d * 4096 + n);
        }
        const unsigned short* hp = (const unsigned short*)&h4;
        const unsigned short* lp = (const unsigned short*)&l4;
#pragma unroll
        for (int i = 0; i < 8; ++i)
            Vs[(ch * 8 + i) * 65 + d] = b2f(hp[i]) + b2f(lp[i]);
    }
    __syncthreads();
    unsigned short* Hh = OHh + (size_t)bz * 262144;
    unsigned short* Hl = OHl + (size_t)bz * 262144;
    const int rbase = wave * 16 + lq * 4;
#pragma unroll
    for (int j = 0; j < 4; ++j) {
        int cc = j * 16 + lm;
        float w[36];
#pragma unroll
        for (int u = 0; u < 36; ++u) w[u] = Vs[(rbase + u) * 65 + cc];
#pragma unroll
        for (int e = 0; e < 4; ++e) {
            float cv = 0.f;
#pragma unroll
            for (int tt = 0; tt < 33; ++tt) cv += w[e + tt] * Ws[tt];
            float o = acc[j][e] * rinv[e] + cv;
            unsigned short hh, ll;
            split2(o, hh, ll);
            size_t off = (size_t)(m0 + rbase + e) * 64 + cc;
            Hh[off] = hh;
            Hl[off] = ll;
        }
    }
}

// ---------------------------------------------------------------------------
// fp32 gemm for attn2 scores
// ---------------------------------------------------------------------------
__global__ __launch_bounds__(256) void gemm_a2(
    const float* __restrict__ A, const float* __restrict__ B,
    float* __restrict__ C) {
    __shared__ float As[16 * 68];
    __shared__ float Bs[16 * 68];
    const int t  = threadIdx.x;
    const int z  = blockIdx.z;
    const int m0 = blockIdx.y * 64;
    const int n0 = blockIdx.x * 64;
    const float* Ab = A + (size_t)z * 16384;
    const float* Bb = B + (size_t)z * 16384;
    float*       Cb = C + (size_t)z * 65536;
    const int tx4 = (t & 15) * 4;
    const int ty4 = (t >> 4) * 4;
    const int ar  = t >> 2, ak = (t & 3) * 4;
    float acc[4][4] = {};
    for (int kt = 0; kt < 64; kt += 16) {
        float4 av = *(const float4*)(Ab + (size_t)(m0 + ar) * 64 + kt + ak);
        float4 bv = *(const float4*)(Bb + (size_t)(n0 + ar) * 64 + kt + ak);
        As[(ak + 0) * 68 + ar] = av.x;
        As[(ak + 1) * 68 + ar] = av.y;
        As[(ak + 2) * 68 + ar] = av.z;
        As[(ak + 3) * 68 + ar] = av.w;
        Bs[(ak + 0) * 68 + ar] = bv.x;
        Bs[(ak + 1) * 68 + ar] = bv.y;
        Bs[(ak + 2) * 68 + ar] = bv.z;
        Bs[(ak + 3) * 68 + ar] = bv.w;
        __syncthreads();
        mt16(As, Bs, ty4, tx4, acc);
        __syncthreads();
    }
#pragma unroll
    for (int u = 0; u < 4; ++u) {
        int row = m0 + ty4 + u;
        *(float4*)(Cb + (size_t)row * 256 + n0 + tx4) =
            make_float4(acc[u][0], acc[u][1], acc[u][2], acc[u][3]);
    }
}

// ---------------------------------------------------------------------------
// small kernels
// ---------------------------------------------------------------------------
__global__ void zero_f(float* __restrict__ p, int n) {
    int i = blockIdx.x * 256 + threadIdx.x;
    if (i < n) p[i] = 0.f;
}

// both landmark means in one dispatch. grid 4096.
__global__ void landmark_mean2(
    const unsigned short* __restrict__ qh, const unsigned short* __restrict__ ql,
    const unsigned short* __restrict__ kh, const unsigned short* __restrict__ kl,
    float* __restrict__ qland, float* __restrict__ kland,
    unsigned short* __restrict__ qlh, unsigned short* __restrict__ qll,
    unsigned short* __restrict__ klh, unsigned short* __restrict__ kll) {
    int o = blockIdx.x * 256 + threadIdx.x;
    bool isq = o < 524288;
    int oo = isq ? o : o - 524288;
    const unsigned short* sh = isq ? qh : kh;
    const unsigned short* sl = isq ? ql : kl;
    float* dst = isq ? qland : kland;
    unsigned short* dh = isq ? qlh : klh;
    unsigned short* dl = isq ? qll : kll;
    int d = oo & 63, m = (oo >> 6) & 255, bh = oo >> 14;
    size_t base = (size_t)bh * 262144 + (size_t)m * 1024 + d;
    float acc = 0.f;
#pragma unroll
    for (int j = 0; j < 16; ++j)
        acc += b2f(sh[base + j * 64]) + b2f(sl[base + j * 64]);
    float v = acc * (1.0f / 16.0f);
    dst[oo] = v;
    unsigned short h, l;
    split2(v, h, l);
    dh[oo] = h;
    dl[oo] = l;
}

// softmax + emit a2 normal/transposed planes + colsum atomics. grid 8192.
__global__ void softmax_fused(const float* __restrict__ a,
                              unsigned short* __restrict__ A2Ph,
                              unsigned short* __restrict__ A2Pl,
                              unsigned short* __restrict__ A2Th,
                              unsigned short* __restrict__ A2Tl,
                              float* __restrict__ colsum) {
    __shared__ float red[256];
    int row = blockIdx.x, t = threadIdx.x;
    float v = a[(size_t)row * 256 + t];
    red[t] = v;
    __syncthreads();
    for (int s = 128; s > 0; s >>= 1) {
        if (t < s) red[t] = fmaxf(red[t], red[t + s]);
        __syncthreads();
    }
    float mx = red[0];
    __syncthreads();
    float e = __expf(v - mx);
    red[t] = e;
    __syncthreads();
    for (int s = 128; s > 0; s >>= 1) {
        if (t < s) red[t] += red[t + s];
        __syncthreads();
    }
    float val = e / red[0];
    int z = row >> 8, r = row & 255;
    atomicAdd(&colsum[z * 256 + t], val);
    unsigned short h, l;
    split2(val, h, l);
    size_t zo = (size_t)z * 65536;
    A2Ph[zo + (size_t)r * 256 + t] = h;
    A2Pl[zo + (size_t)r * 256 + t] = l;
    A2Th[zo + (size_t)t * 256 + r] = h;
    A2Tl[zo + (size_t)t * 256 + r] = l;
}

// global max over colsum -> scal[0]. grid 32.
__global__ void scal_max(const float* __restrict__ colsum,
                         float* __restrict__ scal) {
    __shared__ float red[256];
    int t = threadIdx.x;
    red[t] = colsum[blockIdx.x * 256 + t];
    __syncthreads();
    for (int s = 128; s > 0; s >>= 1) {
        if (t < s) red[t] = fmaxf(red[t], red[t + s]);
        __syncthreads();
    }
    if (t == 0) atomicMax((unsigned int*)&scal[0], __float_as_uint(red[0]));
}

// ---------------------------------------------------------------------------
extern "C" void kernel_launch(void* const* d_in, const int* in_sizes, int n_in,
                              void* d_out, int out_size, void* d_ws, size_t ws_size,
                              hipStream_t stream) {
    const float* x     = (const float*)d_in[0];
    const float* w_qkv = (const float*)d_in[1];
    const float* w_out = (const float*)d_in[2];
    const float* w_res = (const float*)d_in[3];
    float* out = (float*)d_out;
    float* ws  = (float*)d_ws;

    // planes (ushort units)
    unsigned short* Xh  = (unsigned short*)(ws + O_XP);
    unsigned short* Xl  = Xh + 8388608;
    unsigned short* qh  = (unsigned short*)(ws + O_QP);
    unsigned short* ql  = qh + 8388608;
    unsigned short* kh  = (unsigned short*)(ws + O_KP);
    unsigned short* kl  = kh + 8388608;
    unsigned short* vTh = (unsigned short*)(ws + O_VT);
    unsigned short* vTl = vTh + 8388608;
    unsigned short* qlh = (unsigned short*)(ws + O_QLP);
    unsigned short* qll = qlh + 524288;
    unsigned short* klh = (unsigned short*)(ws + O_KLP);
    unsigned short* kll = klh + 524288;

    float* qland = ws + O_QL;
    float* kland = ws + O_KL;
    float* attn2 = ws + O_A2;
    float* t1    = ws + O_T1;
    float* rs3   = ws + O_RS3;
    float* scal  = ws + O_SCAL;
    float* colsum= ws + O_CS;

    // pinv plane pool A: k-plane region (dead after attn3v)
    unsigned short* PBu  = (unsigned short*)(ws + O_KP);
    unsigned short* A2Ph = PBu + 0;
    unsigned short* A2Pl = PBu + 2097152;
    unsigned short* XZNh = PBu + 4194304;
    unsigned short* XZNl = PBu + 6291456;
    unsigned short* XZTh = PBu + 8388608;
    unsigned short* XZTl = PBu + 10485760;
    unsigned short* Y1Th = PBu + 12582912;
    unsigned short* Y1Tl = PBu + 14680064;
    // pinv plane pool B: X-plane region (dead after qkv)
    unsigned short* XRu  = (unsigned short*)(ws + O_XP);
    unsigned short* ZNah = XRu + 0;            // also hosts A2T (pre-iter2)
    unsigned short* ZNal = XRu + 2097152;
    unsigned short* ZNbh = XRu + 4194304;
    unsigned short* ZNbl = XRu + 6291456;
    unsigned short* ZTh_ = XRu + 8388608;
    unsigned short* ZTl_ = XRu + 10485760;
    unsigned short* Y2Th = XRu + 12582912;
    unsigned short* Y2Tl = XRu + 14680064;
    unsigned short* A2Th = ZNah;               // a2^T planes (z0 * denom)
    unsigned short* A2Tl = ZNal;
    // post-pinv aliases
    unsigned short* t2Th = (unsigned short*)(ws + O_QL);   // qland dead
    unsigned short* t2Tl = t2Th + 524288;
    unsigned short* OHh = PBu;                 // pool A dead after pinv
    unsigned short* OHl = PBu + 8388608;

    unsigned short* WQTh = (unsigned short*)(ws + O_WQT);
    unsigned short* WQTl = WQTh + 786432;
    unsigned short* WOTh = (unsigned short*)(ws + O_WOT);
    unsigned short* WOTl = WOTh + 262144;

    zero_f<<<2113, 256, 0, stream>>>(t1, 540688);   // t1+rs3+scal+colsum
    wtrans2<<<4096, 256, 0, stream>>>(w_qkv, w_out, WQTh, WQTl, WOTh, WOTl);
    xsplit<<<8192, 256, 0, stream>>>(x, Xh, Xl);

    mfma_qkv<<<dim3(12, 128), 256, 0, stream>>>(Xh, Xl, WQTh, WQTl,
                                                qh, ql, kh, kl, vTh, vTl);

    landmark_mean2<<<4096, 256, 0, stream>>>(qh, ql, kh, kl, qland, kland,
                                             qlh, qll, klh, kll);

    // F3 first: consumes k planes (pool A overwritten by softmax_fused next)
    attn3v_mfma<<<dim3(8, 4, 32), 256, 0, stream>>>(qlh, qll, kh, kl,
                                                    vTh, vTl, t1, rs3);

    gemm_a2<<<dim3(4, 4, 32), 256, 0, stream>>>(qland, kland, attn2);
    softmax_fused<<<8192, 256, 0, stream>>>(attn2, A2Ph, A2Pl, A2Th, A2Tl,
                                            colsum);
    scal_max<<<32, 256, 0, stream>>>(colsum, scal);

    // pinv: 6x4 all-plane stages (zinit folded into SC modes)
    unsigned short* ZNh[2] = {ZNah, ZNbh};
    unsigned short* ZNl[2] = {ZNal, ZNbl};
    int cur = 0;
    const dim3 pg(4, 4, 32);
    for (int it = 0; it < 6; ++it) {
        if (it == 0) {
            // xz = (1/denom) * (a2 @ a2^T)
            mfma_gemm_p<0, 1, true, true><<<pg, 256, 0, stream>>>(
                A2Ph, A2Pl, A2Ph, A2Pl, XZNh, XZNl, XZTh, XZTl,
                0.f, 0.f, scal);
        } else {
            mfma_gemm_p<0, 0, true, true><<<pg, 256, 0, stream>>>(
                A2Ph, A2Pl, ZTh_, ZTl_, XZNh, XZNl, XZTh, XZTl,
                1.f, 0.f, scal);
        }
        // Y1 = -xz@xz + 7*xz
        mfma_gemm_p<1, 0, false, true><<<pg, 256, 0, stream>>>(
            XZNh, XZNl, XZTh, XZTl, nullptr, nullptr, Y1Th, Y1Tl,
            -1.f, 7.f, scal);
        // Y2 = -xz@Y1 + 15*xz
        mfma_gemm_p<1, 0, false, true><<<pg, 256, 0, stream>>>(
            XZNh, XZNl, Y1Th, Y1Tl, nullptr, nullptr, Y2Th, Y2Tl,
            -1.f, 15.f, scal);
        // z' = -0.25*z@Y2 + 3.25*z
        if (it == 0) {
            // z = a2^T/denom: A = A2T, whole result scaled by 1/denom (SC=2)
            mfma_gemm_p<1, 2, true, true><<<pg, 256, 0, stream>>>(
                A2Th, A2Tl, Y2Th, Y2Tl, ZNbh, ZNbl, ZTh_, ZTl_,
                -0.25f, 3.25f, scal);
            cur = 1;
        } else {
            mfma_gemm_p<1, 0, true, true><<<pg, 256, 0, stream>>>(
                ZNh[cur], ZNl[cur], Y2Th, Y2Tl, ZNh[1 - cur], ZNl[1 - cur],
                ZTh_, ZTl_, -0.25f, 3.25f, scal);
            cur = 1 - cur;
        }
    }
    // zfin = ZN[0] (it1:->0, it2:->1, it3:->0, it4:->1, it5:->0)

    // t2 = zfin @ (t1 / rs3); t2^T planes into dead qland region
    t2_gemm<<<dim3(1, 4, 32), 256, 0, stream>>>(ZNh[0], ZNl[0], t1, rs3,
                                                t2Th, t2Tl);

    // F1 + conv fused -> OH planes (pool A, fully dead now)
    attn1t2_conv<<<dim3(64, 32), 256, 0, stream>>>(qh, ql, klh, kll,
                                                   t2Th, t2Tl, vTh, vTl,
                                                   w_res, OHh, OHl);

    mfma_final<<<dim3(4, 128), 256, 0, stream>>>(OHh, OHl, WOTh, WOTl, out);

    (void)in_sizes; (void)n_in; (void)out_size; (void)ws_size;
}